// Round 4
// baseline (1908.193 us; speedup 1.0000x reference)
//
#include <hip/hip_runtime.h>
#include <hip/hip_bf16.h>

typedef __hip_bfloat16 bf16;
typedef unsigned short ushort8v __attribute__((ext_vector_type(8)));

#define HW 4096
#define IMG_W 64

__device__ __forceinline__ float b2f(bf16 v) { return __bfloat162float(v); }
__device__ __forceinline__ float bfbits2f(unsigned short u) {
    return __uint_as_float(((unsigned int)u) << 16);
}

// ---------------------------------------------------------------------------
// Generic 3x3 SAME conv, NCHW, per-group weights. Inputs fp32 (converted to
// bf16 in LDS), weights fp32, internal activations bf16, accum fp32.
// Block: 256 threads. Tile: 8 rows x 64 cols of pixels, OCB out channels.
// Each thread: 2 pixels (rows tr and tr+4 of the tile) x OCB channels.
// ---------------------------------------------------------------------------
template<int CIN, int COUT, int OCB, bool CONCAT, bool IN_BF16, bool LEAKY, bool OUT_F32>
__global__ __launch_bounds__(256)
void conv3x3_kernel(const void* __restrict__ in0v, const void* __restrict__ in1v,
                    const float* __restrict__ wgt, const float* __restrict__ bias,
                    void* __restrict__ outv)
{
    constexpr int ICC = 32;
    constexpr int NCHUNK = CIN / ICC;
    constexpr int ROWS = 8;

    __shared__ __align__(16) bf16 sIn[ICC][ROWS + 2][IMG_W];
    __shared__ __align__(16) float sW[OCB][ICC][9];

    const int t   = threadIdx.x;
    const int pt  = blockIdx.x;        // pixel tile (8 rows each)
    const int ocb = blockIdx.y;
    const int g   = blockIdx.z;
    const int y0  = pt * ROWS;
    const int oc0 = ocb * OCB;

    const int tr = t >> 6;             // 0..3
    const int x  = t & 63;

    float acc0[OCB], acc1[OCB];
#pragma unroll
    for (int i = 0; i < OCB; ++i) { acc0[i] = 0.f; acc1[i] = 0.f; }

    for (int cc = 0; cc < NCHUNK; ++cc) {
        const int ic0 = cc * ICC;

        // ---- stage input chunk: ICC x (ROWS+2) x 64, 4 elems per thread-iter
        constexpr int TOT4 = ICC * (ROWS + 2) * IMG_W / 4;   // 5120
        for (int i = t; i < TOT4; i += 256) {
            int e   = i * 4;
            int ic  = e / ((ROWS + 2) * IMG_W);
            int rem = e % ((ROWS + 2) * IMG_W);
            int row = rem / IMG_W;
            int col = rem % IMG_W;
            int gy  = y0 - 1 + row;
            bf16 b0, b1c, b2c, b3;
            if (gy >= 0 && gy < 64) {
                int icg = ic0 + ic;
                if (IN_BF16) {
                    const bf16* base = (const bf16*)in0v + (size_t)g * CIN * HW;
                    const bf16* src  = base + (size_t)icg * HW + gy * IMG_W + col;
                    b0 = src[0]; b1c = src[1]; b2c = src[2]; b3 = src[3];
                } else {
                    const float* src;
                    if (CONCAT && icg >= CIN / 2)
                        src = (const float*)in1v + (size_t)(icg - CIN / 2) * HW;
                    else
                        src = (const float*)in0v + (size_t)icg * HW;
                    float4 v = *reinterpret_cast<const float4*>(src + gy * IMG_W + col);
                    b0  = __float2bfloat16(v.x);
                    b1c = __float2bfloat16(v.y);
                    b2c = __float2bfloat16(v.z);
                    b3  = __float2bfloat16(v.w);
                }
            } else {
                b0 = b1c = b2c = b3 = __float2bfloat16(0.f);
            }
            sIn[ic][row][col]     = b0;
            sIn[ic][row][col + 1] = b1c;
            sIn[ic][row][col + 2] = b2c;
            sIn[ic][row][col + 3] = b3;
        }

        // ---- stage weights chunk: OCB x ICC x 9 fp32
        constexpr int WTOT = OCB * ICC * 9;
        for (int i = t; i < WTOT; i += 256) {
            int oc  = i / (ICC * 9);
            int rem = i % (ICC * 9);
            int ic  = rem / 9;
            int tap = rem % 9;
            size_t go = ((size_t)(g * COUT + oc0 + oc) * CIN + (ic0 + ic)) * 9 + tap;
            sW[oc][ic][tap] = wgt[go];
        }
        __syncthreads();

        // ---- compute
        for (int ic = 0; ic < ICC; ++ic) {
            float v0[9], v1[9];
#pragma unroll
            for (int dy = 0; dy < 3; ++dy) {
#pragma unroll
                for (int dx = 0; dx < 3; ++dx) {
                    int cx = x - 1 + dx;
                    bool ok = (cx >= 0) && (cx < 64);
                    int cxc = ok ? cx : 0;
                    float a0 = b2f(sIn[ic][tr + dy][cxc]);
                    float a1 = b2f(sIn[ic][tr + 4 + dy][cxc]);
                    v0[dy * 3 + dx] = ok ? a0 : 0.f;
                    v1[dy * 3 + dx] = ok ? a1 : 0.f;
                }
            }
#pragma unroll
            for (int oc = 0; oc < OCB; ++oc) {
#pragma unroll
                for (int tap = 0; tap < 9; ++tap) {
                    float w = sW[oc][ic][tap];
                    acc0[oc] = fmaf(w, v0[tap], acc0[oc]);
                    acc1[oc] = fmaf(w, v1[tap], acc1[oc]);
                }
            }
        }
        __syncthreads();
    }

    // ---- epilogue
    const int p0 = (y0 + tr) * IMG_W + x;
    const int p1 = (y0 + tr + 4) * IMG_W + x;
#pragma unroll
    for (int oc = 0; oc < OCB; ++oc) {
        float b  = bias[g * COUT + oc0 + oc];
        float r0 = acc0[oc] + b;
        float r1 = acc1[oc] + b;
        if (LEAKY) {
            r0 = r0 >= 0.f ? r0 : 0.1f * r0;
            r1 = r1 >= 0.f ? r1 : 0.1f * r1;
        }
        size_t base = (size_t)(g * COUT + oc0 + oc) * HW;
        if (OUT_F32) {
            ((float*)outv)[base + p0] = r0;
            ((float*)outv)[base + p1] = r1;
        } else {
            ((bf16*)outv)[base + p0] = __float2bfloat16(r0);
            ((bf16*)outv)[base + p1] = __float2bfloat16(r1);
        }
    }
}

// ---------------------------------------------------------------------------
// Transpose gar_feat fp32 [256][4096] -> gar_t bf16 [4096][256] (pixel-major)
// so the warp kernel can do 16B vector gathers over channels.
// ---------------------------------------------------------------------------
__global__ __launch_bounds__(256)
void transpose_kernel(const float* __restrict__ in, bf16* __restrict__ outp)
{
    __shared__ __align__(16) float tile[32][33];
    int bx = blockIdx.x;               // p tile (128)
    int by = blockIdx.y;               // c tile (8)
    int tx = threadIdx.x & 31;
    int ty = threadIdx.x >> 5;         // 0..7
#pragma unroll
    for (int i = 0; i < 4; ++i) {
        int c = by * 32 + ty + i * 8;
        tile[ty + i * 8][tx] = in[(size_t)c * HW + bx * 32 + tx];
    }
    __syncthreads();
#pragma unroll
    for (int i = 0; i < 4; ++i) {
        int p = bx * 32 + ty + i * 8;
        outp[(size_t)p * 256 + by * 32 + tx] = __float2bfloat16(tile[tx][ty + i * 8]);
    }
}

// ---------------------------------------------------------------------------
// Fused softmax-over-groups + bilinear params + warp + combine.
// Block = 256 threads = 8 pixels x 32 channel-chunks (8 ch each).
// Phase 1: threads 0..47 compute per-(pixel,k) softmax'd attn folded into the
//          4 bilinear corner weights for all 8 groups -> LDS.
// Phase 2: every thread gathers 4 corners x 8 channels per (g,k) and
//          accumulates mask-weighted output.
// out[c][p] = sum_g mask[g][c] * sum_k attn*bilinear(gar, c, grid_{g,k}(p))
// Output fp32 (the reference's output dtype).
// ---------------------------------------------------------------------------
__global__ __launch_bounds__(256)
void warp_combine_kernel(const float* __restrict__ oa,
                         const bf16* __restrict__ gar_t,
                         const float* __restrict__ mask,
                         float* __restrict__ out)
{
    __shared__ __align__(16) float4 sWts[8][6][8];  // [lp][k][g]
    __shared__ __align__(16) int4   sIdx[8][6][8];

    const int t = threadIdx.x;

    // ---------------- phase 1: params ----------------
    if (t < 48) {
        int lp = t / 6;
        int k  = t % 6;
        int p  = blockIdx.x * 8 + lp;
        int x  = p & 63, y = p >> 6;

        float l[8];
        float m = -1e30f;
#pragma unroll
        for (int g = 0; g < 8; ++g) {
            l[g] = oa[(size_t)(g * 18 + 12 + k) * HW + p];
            m = fmaxf(m, l[g]);
        }
        float s = 0.f;
#pragma unroll
        for (int g = 0; g < 8; ++g) { l[g] = __expf(l[g] - m); s += l[g]; }
        float inv = 1.f / s;

#pragma unroll
        for (int g = 0; g < 8; ++g) {
            float a  = l[g] * inv;
            float ox = oa[(size_t)(g * 18 + 2 * k)     * HW + p];
            float oy = oa[(size_t)(g * 18 + 2 * k + 1) * HW + p];
            // composed apply_offset + grid_sample(border, align_corners=False):
            // sx = clip((x+ox)*64/63 - 0.5, 0, 63)
            float sx = fminf(fmaxf(((float)x + ox) * (64.f / 63.f) - 0.5f, 0.f), 63.f);
            float sy = fminf(fmaxf(((float)y + oy) * (64.f / 63.f) - 0.5f, 0.f), 63.f);
            float fx0 = floorf(sx), fy0 = floorf(sy);
            int   x0 = (int)fx0,    y0i = (int)fy0;
            float wx = sx - fx0,    wy = sy - fy0;
            int   x1 = min(x0 + 1, 63), y1 = min(y0i + 1, 63);
            sWts[lp][k][g] = make_float4(a * (1.f - wy) * (1.f - wx),
                                         a * (1.f - wy) * wx,
                                         a * wy * (1.f - wx),
                                         a * wy * wx);
            sIdx[lp][k][g] = make_int4(y0i * 64 + x0, y0i * 64 + x1,
                                       y1  * 64 + x0, y1  * 64 + x1);
        }
    }
    __syncthreads();

    // ---------------- phase 2: gather + combine ----------------
    const int lp = t >> 5;
    const int p  = blockIdx.x * 8 + lp;
    const int c0 = (t & 31) * 8;

    float acc[8];
#pragma unroll
    for (int j = 0; j < 8; ++j) acc[j] = 0.f;

    for (int g = 0; g < 8; ++g) {
        float4 m0 = *reinterpret_cast<const float4*>(mask + g * 256 + c0);
        float4 m1 = *reinterpret_cast<const float4*>(mask + g * 256 + c0 + 4);
        float mk[8] = {m0.x, m0.y, m0.z, m0.w, m1.x, m1.y, m1.z, m1.w};
#pragma unroll
        for (int k = 0; k < 6; ++k) {
            float4 w  = sWts[lp][k][g];
            int4   id = sIdx[lp][k][g];
            ushort8v v00 = *reinterpret_cast<const ushort8v*>(gar_t + (size_t)id.x * 256 + c0);
            ushort8v v01 = *reinterpret_cast<const ushort8v*>(gar_t + (size_t)id.y * 256 + c0);
            ushort8v v10 = *reinterpret_cast<const ushort8v*>(gar_t + (size_t)id.z * 256 + c0);
            ushort8v v11 = *reinterpret_cast<const ushort8v*>(gar_t + (size_t)id.w * 256 + c0);
#pragma unroll
            for (int j = 0; j < 8; ++j) {
                float sv = w.x * bfbits2f(v00[j]) + w.y * bfbits2f(v01[j])
                         + w.z * bfbits2f(v10[j]) + w.w * bfbits2f(v11[j]);
                acc[j] = fmaf(mk[j], sv, acc[j]);
            }
        }
    }
#pragma unroll
    for (int j = 0; j < 8; ++j)
        out[(size_t)(c0 + j) * HW + p] = acc[j];
}

// ---------------------------------------------------------------------------
// Workspace layout (peak 14 MB, with reuse):
//   [0,  8M)   hid1 [8][128][4096] bf16      (dead after conv2)
//   [8M, 12M)  hid2 [8][64][4096]  bf16      (dead after conv3)
//   [12M,14M)  hid3 [8][32][4096]  bf16      (dead after conv4)
//   [0, 2.25M) oa   [8][18][4096]  fp32      (overlays dead hid1; conv4 out)
//   [4M, 6M)   gar_t [4096][256]   bf16      (overlays dead hid1 tail)
// Order: conv1..conv4, then transpose, then fused warp.
// ---------------------------------------------------------------------------
extern "C" void kernel_launch(void* const* d_in, const int* in_sizes, int n_in,
                              void* d_out, int out_size, void* d_ws, size_t ws_size,
                              hipStream_t stream)
{
    (void)in_sizes; (void)n_in; (void)out_size; (void)ws_size;
    // Reference setup_inputs() and output are jnp.float32 -> fp32 I/O.
    // (Round-2 NaN proved inputs are fp32; round-3 finite-wrong with the
    //  packed-bf16 signature proved the output buffer is fp32 too.)
    const float* gar  = (const float*)d_in[0];
    const float* cond = (const float*)d_in[1];
    const float* mask = (const float*)d_in[2];
    const float* W1   = (const float*)d_in[3];
    const float* b1   = (const float*)d_in[4];
    const float* W2   = (const float*)d_in[5];
    const float* b2   = (const float*)d_in[6];
    const float* W3   = (const float*)d_in[7];
    const float* b3   = (const float*)d_in[8];
    const float* W4   = (const float*)d_in[9];
    const float* b4   = (const float*)d_in[10];
    float* out = (float*)d_out;

    char* ws = (char*)d_ws;
    bf16*  hid1  = (bf16*)(ws);
    bf16*  hid2  = (bf16*)(ws + 8388608);
    bf16*  hid3  = (bf16*)(ws + 12582912);
    float* oa    = (float*)(ws);              // overlays dead hid1
    bf16*  gar_t = (bf16*)(ws + 4194304);     // overlays dead hid1 tail

    conv3x3_kernel<512, 128, 16, true,  false, true,  false>
        <<<dim3(8, 8, 8), 256, 0, stream>>>(gar, cond, W1, b1, hid1);
    conv3x3_kernel<128, 64, 16, false, true,  true,  false>
        <<<dim3(8, 4, 8), 256, 0, stream>>>(hid1, hid1, W2, b2, hid2);
    conv3x3_kernel<64, 32, 16, false, true,  true,  false>
        <<<dim3(8, 2, 8), 256, 0, stream>>>(hid2, hid2, W3, b3, hid3);
    conv3x3_kernel<32, 18, 18, false, true,  false, true>
        <<<dim3(8, 1, 8), 256, 0, stream>>>(hid3, hid3, W4, b4, oa);

    transpose_kernel<<<dim3(128, 8), 256, 0, stream>>>(gar, gar_t);

    warp_combine_kernel<<<512, 256, 0, stream>>>(oa, gar_t, mask, out);
}

// Round 5
// 508.449 us; speedup vs baseline: 3.7530x; 3.7530x over previous
//
#include <hip/hip_runtime.h>
#include <hip/hip_bf16.h>

typedef __hip_bfloat16 bf16;
typedef unsigned short ushort8v __attribute__((ext_vector_type(8)));
typedef short  s16x4  __attribute__((ext_vector_type(4)));
typedef short  bf16x8 __attribute__((ext_vector_type(8)));   // 8 bf16 (4 VGPRs)
typedef float  f32x4  __attribute__((ext_vector_type(4)));

#define HW 4096
#define IMG_W 64

__device__ __forceinline__ float b2f(bf16 v) { return __bfloat162float(v); }
__device__ __forceinline__ float bfbits2f(unsigned short u) {
    return __uint_as_float(((unsigned int)u) << 16);
}
__device__ __forceinline__ short f2bs(float f) {
    bf16 h = __float2bfloat16(f);
    return *reinterpret_cast<short*>(&h);
}

// ---------------------------------------------------------------------------
// Implicit-GEMM 3x3 SAME conv via bf16 MFMA 16x16x32.
// Tile: BM=128 pixels (2 image rows, halo-staged as 4 rows), BN=64 out-chans.
// K = CIN*9, looped as (32-ic chunk) x (dy) with 3 dx-taps staged per phase.
// Waves 2x2: wave&1 -> image row, wave>>1 -> 32-oc half; per dx-step each
// wave reads 2 W-frags + 4 P-frags and issues 8 MFMAs.
// Weights are the MFMA A-operand (m=oc), pixels B-operand (n=pixel) so C/D
// lanes (col=lane&15) map to consecutive pixels -> coalesced stores.
// sA cols padded +2 (zero cols at idx 0,65) for SAME x-padding; ic padded
// 32->40 so ds_read_b128 is 16B-aligned with period-8 bank rotation.
// XCD swizzle: blockIdx&7 selects the group -> per-XCD weight slice stays
// L2-resident (heuristic only; correctness unaffected).
// ---------------------------------------------------------------------------
template<int CIN, int COUT, int NT, bool CONCAT>
__global__ __launch_bounds__(256)
void conv3x3_mfma(const void* __restrict__ in0v, const void* __restrict__ in1v,
                  const float* __restrict__ wgt, const float* __restrict__ bias,
                  short* __restrict__ outp)
{
    constexpr int NCC = CIN / 32;
    constexpr int BN  = 64;

    __shared__ short sA[4][66][40];    // [halo row][img col + 1][ic pad]
    __shared__ short sB[BN][3][40];    // [oc][dx][ic pad]

    const int b   = blockIdx.x;
    const int gnt = (b & 7) + 8 * (b >> 8);       // group/n-tile composite
    const int pt  = (b >> 3) & 31;                // pixel tile (2 rows each)
    const int g   = gnt & 7;
    const int nt  = (NT == 2) ? (gnt >> 3) : 0;
    const int oc0 = nt * BN;
    const int r0  = pt * 2;

    const int t    = threadIdx.x;
    const int wave = t >> 6, lane = t & 63;
    const int l15  = lane & 15, quad = lane >> 4;
    const int row_l = wave & 1;                   // which of the 2 image rows
    const int ocw   = (wave >> 1) * 32;           // 32-oc half within BN
    const int k0    = quad * 8;                   // k-offset within 32-chunk

    f32x4 acc[2][4];
#pragma unroll
    for (int o = 0; o < 2; ++o)
#pragma unroll
        for (int p = 0; p < 4; ++p)
#pragma unroll
            for (int r = 0; r < 4; ++r) acc[o][p][r] = 0.f;

    for (int cc = 0; cc < NCC; ++cc) {
        for (int dy = 0; dy < 3; ++dy) {
            if (dy == 0) {
                // zero-fill the two halo columns once (never overwritten)
                if (cc == 0 && t < 64) {
                    int rr = (t >> 4) & 3;
                    int cp = ((t >> 3) & 1) ? 65 : 0;
                    int i0 = (t & 7) * 4;
                    s16x4 z = {0, 0, 0, 0};
                    *reinterpret_cast<s16x4*>(&sA[rr][cp][i0]) = z;
                }
                // stage input chunk: 4 halo rows x 64 cols x 32 ic
                const int col = t & 63, rq = t >> 6;
                const int gy  = r0 - 1 + rq;
                const bool in_img = (gy >= 0 && gy < 64);
#pragma unroll
                for (int s = 0; s < 8; ++s) {
                    s16x4 v = {0, 0, 0, 0};
                    if (in_img) {
                        const int icb = cc * 32 + s * 4;
#pragma unroll
                        for (int j = 0; j < 4; ++j) {
                            if (CONCAT) {
                                const float* sp = (icb + j < CIN / 2)
                                    ? ((const float*)in0v + (size_t)(icb + j) * HW)
                                    : ((const float*)in1v + (size_t)(icb + j - CIN / 2) * HW);
                                v[j] = f2bs(sp[gy * IMG_W + col]);
                            } else {
                                const short* sp = (const short*)in0v
                                    + ((size_t)g * CIN + icb + j) * HW;
                                v[j] = sp[gy * IMG_W + col];
                            }
                        }
                    }
                    *reinterpret_cast<s16x4*>(&sA[rq][col + 1][s * 4]) = v;
                }
            }
            // stage weights: BN oc x 3 dx x 32 ic for (cc, dy)
            {
                const float* wb = wgt
                    + ((size_t)(g * COUT + oc0) * CIN + cc * 32) * 9 + dy * 3;
#pragma unroll
                for (int ii = 0; ii < 6; ++ii) {
                    int i   = t + ii * 256;       // 0..1535
                    int oc  = i / 24;
                    int rem = i % 24;
                    int dx  = rem % 3;
                    int q   = rem / 3;
                    s16x4 v;
#pragma unroll
                    for (int j = 0; j < 4; ++j)
                        v[j] = f2bs(wb[((size_t)oc * CIN + q * 4 + j) * 9 + dx]);
                    *reinterpret_cast<s16x4*>(&sB[oc][dx][q * 4]) = v;
                }
            }
            __syncthreads();

#pragma unroll
            for (int dx = 0; dx < 3; ++dx) {
                bf16x8 pF[4], wF[2];
#pragma unroll
                for (int p = 0; p < 4; ++p)
                    pF[p] = *reinterpret_cast<const bf16x8*>(
                        &sA[row_l + dy][p * 16 + l15 + dx][k0]);
#pragma unroll
                for (int o = 0; o < 2; ++o)
                    wF[o] = *reinterpret_cast<const bf16x8*>(
                        &sB[ocw + o * 16 + l15][dx][k0]);
#pragma unroll
                for (int o = 0; o < 2; ++o)
#pragma unroll
                    for (int p = 0; p < 4; ++p)
                        acc[o][p] = __builtin_amdgcn_mfma_f32_16x16x32_bf16(
                            wF[o], pF[p], acc[o][p], 0, 0, 0);
            }
            __syncthreads();
        }
    }

    // epilogue: bias + leaky, bf16 store. C/D: m(oc)=quad*4+reg, n(pix)=l15.
    const int prow = r0 + row_l;
#pragma unroll
    for (int o = 0; o < 2; ++o)
#pragma unroll
        for (int reg = 0; reg < 4; ++reg) {
            int ocl  = ocw + o * 16 + quad * 4 + reg;
            float bv = bias[g * COUT + oc0 + ocl];
            size_t base = ((size_t)(g * COUT + oc0 + ocl)) * HW + prow * IMG_W;
#pragma unroll
            for (int p = 0; p < 4; ++p) {
                float v = acc[o][p][reg] + bv;
                v = v >= 0.f ? v : 0.1f * v;
                outp[base + p * 16 + l15] = f2bs(v);
            }
        }
}

// ---------------------------------------------------------------------------
// VALU 3x3 conv (proven-correct) — used for the small tail convs (conv3/4).
// ---------------------------------------------------------------------------
template<int CIN, int COUT, int OCB, bool CONCAT, bool IN_BF16, bool LEAKY, bool OUT_F32>
__global__ __launch_bounds__(256)
void conv3x3_kernel(const void* __restrict__ in0v, const void* __restrict__ in1v,
                    const float* __restrict__ wgt, const float* __restrict__ bias,
                    void* __restrict__ outv)
{
    constexpr int ICC = 32;
    constexpr int NCHUNK = CIN / ICC;
    constexpr int ROWS = 8;

    __shared__ __align__(16) bf16 sIn[ICC][ROWS + 2][IMG_W];
    __shared__ __align__(16) float sW[OCB][ICC][9];

    const int t   = threadIdx.x;
    const int pt  = blockIdx.x;
    const int ocb = blockIdx.y;
    const int g   = blockIdx.z;
    const int y0  = pt * ROWS;
    const int oc0 = ocb * OCB;

    const int tr = t >> 6;
    const int x  = t & 63;

    float acc0[OCB], acc1[OCB];
#pragma unroll
    for (int i = 0; i < OCB; ++i) { acc0[i] = 0.f; acc1[i] = 0.f; }

    for (int cc = 0; cc < NCHUNK; ++cc) {
        const int ic0 = cc * ICC;

        constexpr int TOT4 = ICC * (ROWS + 2) * IMG_W / 4;
        for (int i = t; i < TOT4; i += 256) {
            int e   = i * 4;
            int ic  = e / ((ROWS + 2) * IMG_W);
            int rem = e % ((ROWS + 2) * IMG_W);
            int row = rem / IMG_W;
            int col = rem % IMG_W;
            int gy  = y0 - 1 + row;
            bf16 b0, b1c, b2c, b3;
            if (gy >= 0 && gy < 64) {
                int icg = ic0 + ic;
                if (IN_BF16) {
                    const bf16* base = (const bf16*)in0v + (size_t)g * CIN * HW;
                    const bf16* src  = base + (size_t)icg * HW + gy * IMG_W + col;
                    b0 = src[0]; b1c = src[1]; b2c = src[2]; b3 = src[3];
                } else {
                    const float* src;
                    if (CONCAT && icg >= CIN / 2)
                        src = (const float*)in1v + (size_t)(icg - CIN / 2) * HW;
                    else
                        src = (const float*)in0v + (size_t)icg * HW;
                    float4 v = *reinterpret_cast<const float4*>(src + gy * IMG_W + col);
                    b0  = __float2bfloat16(v.x);
                    b1c = __float2bfloat16(v.y);
                    b2c = __float2bfloat16(v.z);
                    b3  = __float2bfloat16(v.w);
                }
            } else {
                b0 = b1c = b2c = b3 = __float2bfloat16(0.f);
            }
            sIn[ic][row][col]     = b0;
            sIn[ic][row][col + 1] = b1c;
            sIn[ic][row][col + 2] = b2c;
            sIn[ic][row][col + 3] = b3;
        }

        constexpr int WTOT = OCB * ICC * 9;
        for (int i = t; i < WTOT; i += 256) {
            int oc  = i / (ICC * 9);
            int rem = i % (ICC * 9);
            int ic  = rem / 9;
            int tap = rem % 9;
            size_t go = ((size_t)(g * COUT + oc0 + oc) * CIN + (ic0 + ic)) * 9 + tap;
            sW[oc][ic][tap] = wgt[go];
        }
        __syncthreads();

        for (int ic = 0; ic < ICC; ++ic) {
            float v0[9], v1[9];
#pragma unroll
            for (int dy = 0; dy < 3; ++dy) {
#pragma unroll
                for (int dx = 0; dx < 3; ++dx) {
                    int cx = x - 1 + dx;
                    bool ok = (cx >= 0) && (cx < 64);
                    int cxc = ok ? cx : 0;
                    float a0 = b2f(sIn[ic][tr + dy][cxc]);
                    float a1 = b2f(sIn[ic][tr + 4 + dy][cxc]);
                    v0[dy * 3 + dx] = ok ? a0 : 0.f;
                    v1[dy * 3 + dx] = ok ? a1 : 0.f;
                }
            }
#pragma unroll
            for (int oc = 0; oc < OCB; ++oc) {
#pragma unroll
                for (int tap = 0; tap < 9; ++tap) {
                    float w = sW[oc][ic][tap];
                    acc0[oc] = fmaf(w, v0[tap], acc0[oc]);
                    acc1[oc] = fmaf(w, v1[tap], acc1[oc]);
                }
            }
        }
        __syncthreads();
    }

    const int p0 = (y0 + tr) * IMG_W + x;
    const int p1 = (y0 + tr + 4) * IMG_W + x;
#pragma unroll
    for (int oc = 0; oc < OCB; ++oc) {
        float b  = bias[g * COUT + oc0 + oc];
        float r0 = acc0[oc] + b;
        float r1 = acc1[oc] + b;
        if (LEAKY) {
            r0 = r0 >= 0.f ? r0 : 0.1f * r0;
            r1 = r1 >= 0.f ? r1 : 0.1f * r1;
        }
        size_t base = (size_t)(g * COUT + oc0 + oc) * HW;
        if (OUT_F32) {
            ((float*)outv)[base + p0] = r0;
            ((float*)outv)[base + p1] = r1;
        } else {
            ((bf16*)outv)[base + p0] = __float2bfloat16(r0);
            ((bf16*)outv)[base + p1] = __float2bfloat16(r1);
        }
    }
}

// ---------------------------------------------------------------------------
// Transpose gar_feat fp32 [256][4096] -> gar_t bf16 [4096][256] (pixel-major).
// ---------------------------------------------------------------------------
__global__ __launch_bounds__(256)
void transpose_kernel(const float* __restrict__ in, bf16* __restrict__ outp)
{
    __shared__ __align__(16) float tile[32][33];
    int bx = blockIdx.x;
    int by = blockIdx.y;
    int tx = threadIdx.x & 31;
    int ty = threadIdx.x >> 5;
#pragma unroll
    for (int i = 0; i < 4; ++i) {
        int c = by * 32 + ty + i * 8;
        tile[ty + i * 8][tx] = in[(size_t)c * HW + bx * 32 + tx];
    }
    __syncthreads();
#pragma unroll
    for (int i = 0; i < 4; ++i) {
        int p = bx * 32 + ty + i * 8;
        outp[(size_t)p * 256 + by * 32 + tx] = __float2bfloat16(tile[tx][ty + i * 8]);
    }
}

// ---------------------------------------------------------------------------
// Fused softmax-over-groups + bilinear params + warp + combine (fp32 out).
// ---------------------------------------------------------------------------
__global__ __launch_bounds__(256)
void warp_combine_kernel(const float* __restrict__ oa,
                         const bf16* __restrict__ gar_t,
                         const float* __restrict__ mask,
                         float* __restrict__ out)
{
    __shared__ __align__(16) float4 sWts[8][6][8];
    __shared__ __align__(16) int4   sIdx[8][6][8];

    const int t = threadIdx.x;

    if (t < 48) {
        int lp = t / 6;
        int k  = t % 6;
        int p  = blockIdx.x * 8 + lp;
        int x  = p & 63, y = p >> 6;

        float l[8];
        float m = -1e30f;
#pragma unroll
        for (int g = 0; g < 8; ++g) {
            l[g] = oa[(size_t)(g * 18 + 12 + k) * HW + p];
            m = fmaxf(m, l[g]);
        }
        float s = 0.f;
#pragma unroll
        for (int g = 0; g < 8; ++g) { l[g] = __expf(l[g] - m); s += l[g]; }
        float inv = 1.f / s;

#pragma unroll
        for (int g = 0; g < 8; ++g) {
            float a  = l[g] * inv;
            float ox = oa[(size_t)(g * 18 + 2 * k)     * HW + p];
            float oy = oa[(size_t)(g * 18 + 2 * k + 1) * HW + p];
            float sx = fminf(fmaxf(((float)x + ox) * (64.f / 63.f) - 0.5f, 0.f), 63.f);
            float sy = fminf(fmaxf(((float)y + oy) * (64.f / 63.f) - 0.5f, 0.f), 63.f);
            float fx0 = floorf(sx), fy0 = floorf(sy);
            int   x0 = (int)fx0,    y0i = (int)fy0;
            float wx = sx - fx0,    wy = sy - fy0;
            int   x1 = min(x0 + 1, 63), y1 = min(y0i + 1, 63);
            sWts[lp][k][g] = make_float4(a * (1.f - wy) * (1.f - wx),
                                         a * (1.f - wy) * wx,
                                         a * wy * (1.f - wx),
                                         a * wy * wx);
            sIdx[lp][k][g] = make_int4(y0i * 64 + x0, y0i * 64 + x1,
                                       y1  * 64 + x0, y1  * 64 + x1);
        }
    }
    __syncthreads();

    const int lp = t >> 5;
    const int p  = blockIdx.x * 8 + lp;
    const int c0 = (t & 31) * 8;

    float acc[8];
#pragma unroll
    for (int j = 0; j < 8; ++j) acc[j] = 0.f;

    for (int g = 0; g < 8; ++g) {
        float4 m0 = *reinterpret_cast<const float4*>(mask + g * 256 + c0);
        float4 m1 = *reinterpret_cast<const float4*>(mask + g * 256 + c0 + 4);
        float mk[8] = {m0.x, m0.y, m0.z, m0.w, m1.x, m1.y, m1.z, m1.w};
#pragma unroll
        for (int k = 0; k < 6; ++k) {
            float4 w  = sWts[lp][k][g];
            int4   id = sIdx[lp][k][g];
            ushort8v v00 = *reinterpret_cast<const ushort8v*>(gar_t + (size_t)id.x * 256 + c0);
            ushort8v v01 = *reinterpret_cast<const ushort8v*>(gar_t + (size_t)id.y * 256 + c0);
            ushort8v v10 = *reinterpret_cast<const ushort8v*>(gar_t + (size_t)id.z * 256 + c0);
            ushort8v v11 = *reinterpret_cast<const ushort8v*>(gar_t + (size_t)id.w * 256 + c0);
#pragma unroll
            for (int j = 0; j < 8; ++j) {
                float sv = w.x * bfbits2f(v00[j]) + w.y * bfbits2f(v01[j])
                         + w.z * bfbits2f(v10[j]) + w.w * bfbits2f(v11[j]);
                acc[j] = fmaf(mk[j], sv, acc[j]);
            }
        }
    }
#pragma unroll
    for (int j = 0; j < 8; ++j)
        out[(size_t)(c0 + j) * HW + p] = acc[j];
}

// ---------------------------------------------------------------------------
extern "C" void kernel_launch(void* const* d_in, const int* in_sizes, int n_in,
                              void* d_out, int out_size, void* d_ws, size_t ws_size,
                              hipStream_t stream)
{
    (void)in_sizes; (void)n_in; (void)out_size; (void)ws_size;
    const float* gar  = (const float*)d_in[0];
    const float* cond = (const float*)d_in[1];
    const float* mask = (const float*)d_in[2];
    const float* W1   = (const float*)d_in[3];
    const float* b1   = (const float*)d_in[4];
    const float* W2   = (const float*)d_in[5];
    const float* b2   = (const float*)d_in[6];
    const float* W3   = (const float*)d_in[7];
    const float* b3   = (const float*)d_in[8];
    const float* W4   = (const float*)d_in[9];
    const float* b4   = (const float*)d_in[10];
    float* out = (float*)d_out;

    char* ws = (char*)d_ws;
    short* hid1  = (short*)(ws);                  //  8 MB [8][128][4096] bf16
    short* hid2  = (short*)(ws + 8388608);        //  4 MB [8][64][4096]  bf16
    bf16*  hid3  = (bf16*)(ws + 12582912);        //  2 MB [8][32][4096]  bf16
    float* oa    = (float*)(ws);                  // overlays dead hid1
    bf16*  gar_t = (bf16*)(ws + 4194304);         // overlays dead hid1 tail

    conv3x3_mfma<512, 128, 2, true>
        <<<512, 256, 0, stream>>>(gar, cond, W1, b1, hid1);
    conv3x3_mfma<128, 64, 1, false>
        <<<256, 256, 0, stream>>>(hid1, nullptr, W2, b2, hid2);

    conv3x3_kernel<64, 32, 16, false, true, true, false>
        <<<dim3(8, 2, 8), 256, 0, stream>>>(hid2, hid2, W3, b3, hid3);
    conv3x3_kernel<32, 18, 18, false, true, false, true>
        <<<dim3(8, 1, 8), 256, 0, stream>>>(hid3, hid3, W4, b4, oa);

    transpose_kernel<<<dim3(128, 8), 256, 0, stream>>>(gar, gar_t);

    warp_combine_kernel<<<512, 256, 0, stream>>>(oa, gar_t, mask, out);
}

// Round 6
// 436.811 us; speedup vs baseline: 4.3685x; 1.1640x over previous
//
#include <hip/hip_runtime.h>
#include <hip/hip_bf16.h>

typedef __hip_bfloat16 bf16;
typedef unsigned short ushort8v __attribute__((ext_vector_type(8)));
typedef short  s16x4  __attribute__((ext_vector_type(4)));
typedef short  bf16x8 __attribute__((ext_vector_type(8)));   // 8 bf16 (4 VGPRs)
typedef float  f32x4  __attribute__((ext_vector_type(4)));

#define HW 4096
#define IMG_W 64

__device__ __forceinline__ float b2f(bf16 v) { return __bfloat162float(v); }
__device__ __forceinline__ float bfbits2f(unsigned short u) {
    return __uint_as_float(((unsigned int)u) << 16);
}
__device__ __forceinline__ short f2bs(float f) {
    bf16 h = __float2bfloat16(f);
    return *reinterpret_cast<short*>(&h);
}

// async global->LDS, 16B per lane. LDS dest is wave-uniform base; HW scatters
// lane i's 16B to base + i*16 (m97/m104 semantics).
__device__ __forceinline__ void gl_lds16(const void* g, void* s) {
    __builtin_amdgcn_global_load_lds(
        (const __attribute__((address_space(1))) unsigned int*)g,
        (__attribute__((address_space(3))) unsigned int*)s, 16, 0, 0);
}

// ---------------------------------------------------------------------------
// pack_input: concat(gar,cond) fp32 [512][4096] -> inp_t bf16 [4096][512]
// (pixel-major). inp_t[:, 0:256] doubles as gar_t for the warp kernel.
// ---------------------------------------------------------------------------
__global__ __launch_bounds__(256)
void pack_input(const float* __restrict__ gar, const float* __restrict__ cond,
                short* __restrict__ outp)
{
    __shared__ __align__(16) float tile[32][33];
    int bx = blockIdx.x;               // px tile (128)
    int by = blockIdx.y;               // ch tile (16)
    int tx = threadIdx.x & 31;
    int ty = threadIdx.x >> 5;
#pragma unroll
    for (int i = 0; i < 4; ++i) {
        int c = by * 32 + ty + i * 8;
        const float* src = (c < 256) ? (gar + (size_t)c * HW)
                                     : (cond + (size_t)(c - 256) * HW);
        tile[ty + i * 8][tx] = src[bx * 32 + tx];
    }
    __syncthreads();
#pragma unroll
    for (int i = 0; i < 4; ++i) {
        int p = bx * 32 + ty + i * 8;
        outp[(size_t)p * 512 + by * 32 + tx] = f2bs(tile[tx][ty + i * 8]);
    }
}

// ---------------------------------------------------------------------------
// pack_weights: W fp32 [G][COUT][CIN][3][3] -> bf16 blocks
// [g][nt][cc][64oc][9tap][40ic] (ic 32 payload + 8 zero pad), 46080 B/block,
// contiguous so the conv kernel can stage one block with 45 global_load_lds.
// ---------------------------------------------------------------------------
template<int CIN, int COUT, int NT>
__global__ __launch_bounds__(256)
void pack_weights(const float* __restrict__ wgt, char* __restrict__ wp)
{
    constexpr int NCC = CIN / 32;
    __shared__ __align__(16) short sT[64][9][40];

    const int t  = threadIdx.x;
    const int bx = blockIdx.x;                 // g*NT*NCC + nt*NCC + cc
    const int cc = bx % NCC;
    const int nt = (bx / NCC) % NT;
    const int g  = bx / (NT * NCC);

    // zero (covers the ic pad)
    for (int i = t; i < 64 * 9 * 10; i += 256)
        *reinterpret_cast<s16x4*>(&sT[0][0][0] + i * 4) = s16x4{0, 0, 0, 0};
    __syncthreads();

    const size_t base = ((size_t)(g * COUT + nt * 64) * CIN + cc * 32) * 9;
    for (int i = t; i < 64 * 288; i += 256) {
        int oc = i / 288;
        int r  = i % 288;                      // ic*9 + tap
        int ic = r / 9, tap = r % 9;
        sT[oc][tap][ic] = f2bs(wgt[base + (size_t)oc * CIN * 9 + r]);
    }
    __syncthreads();

    const short* src = &sT[0][0][0];
    short* dst = (short*)(wp + (size_t)bx * 46080);
    for (int i = t; i < 2880; i += 256)
        *reinterpret_cast<s16x4*>(dst + i * 8 + 4) = *(s16x4*)0;  // placeholder (unused)
}

// The placeholder above is wrong style; define the real writer separately to
// keep the hot path simple: rewrite pack_weights tail correctly below.
// (We re-implement pack_weights fully — the template above is superseded.)

template<int CIN, int COUT, int NT>
__global__ __launch_bounds__(256)
void pack_weights2(const float* __restrict__ wgt, char* __restrict__ wp)
{
    constexpr int NCC = CIN / 32;
    __shared__ __align__(16) short sT[64][9][40];

    const int t  = threadIdx.x;
    const int bx = blockIdx.x;
    const int cc = bx % NCC;
    const int nt = (bx / NCC) % NT;
    const int g  = bx / (NT * NCC);

    for (int i = t; i < 64 * 9 * 10; i += 256)
        *reinterpret_cast<s16x4*>(&sT[0][0][0] + (size_t)i * 4) = s16x4{0, 0, 0, 0};
    __syncthreads();

    const size_t base = ((size_t)(g * COUT + nt * 64) * CIN + cc * 32) * 9;
    for (int i = t; i < 64 * 288; i += 256) {
        int oc = i / 288;
        int r  = i % 288;
        int ic = r / 9, tap = r % 9;
        sT[oc][tap][ic] = f2bs(wgt[base + (size_t)oc * CIN * 9 + r]);
    }
    __syncthreads();

    const s16x4* src = reinterpret_cast<const s16x4*>(&sT[0][0][0]);
    s16x4* dst = reinterpret_cast<s16x4*>(wp + (size_t)bx * 46080);
    for (int i = t; i < 5760; i += 256)        // 5760 * 8B = 46080
        dst[i] = src[i];
}

// ---------------------------------------------------------------------------
// Implicit-GEMM 3x3 conv, bf16 MFMA 16x16x32, v2.
// Input pixel-major bf16 [.. px ..][ICP]; weights prepacked (see above).
// Tile: ROWS image rows (BM=ROWS*64 px) x 64 oc. 4 waves:
//   ROWS=4: wave -> row, each wave 4 p-frags x 4 o-frags (16 MFMA / 8 reads)
//   ROWS=2: wave -> (row, 32-oc half), 4 p-frags x 2 o-frags
// Per cc-phase: stage sA (VGPR b128) + sB (global_load_lds), then 9 taps.
// ---------------------------------------------------------------------------
template<int ICP, int COUT, int ROWS, int OF, int NT, bool PIXMAJ_OUT>
__global__ __launch_bounds__(256)
void conv_mfma(const short* __restrict__ inp, const char* __restrict__ wp,
               const float* __restrict__ bias, short* __restrict__ outp)
{
    constexpr int NCC  = ICP / 32;
    constexpr int HALO = ROWS + 2;
    constexpr int NPT  = 4096 / (ROWS * 64);

    __shared__ __align__(16) short sA[HALO][66][40];
    __shared__ __align__(16) short sB[64][9][40];   // 46080 B = 45 KiB

    const int b  = blockIdx.x;
    const int g  = b & 7;                     // XCD swizzle: group per XCD
    const int r_ = b >> 3;
    const int pt = r_ % NPT;
    const int nt = r_ / NPT;
    const int r0 = pt * ROWS;

    const int t    = threadIdx.x;
    const int wave = t >> 6, lane = t & 63;
    const int l15  = lane & 15, quad = lane >> 4;
    const int row_l = (ROWS == 4) ? wave : (wave & 1);
    const int ocw   = (ROWS == 4) ? 0 : (wave >> 1) * 32;
    const int k0    = quad * 8;

    const size_t gpix = (ICP == 512) ? 0 : ((size_t)g * 4096);   // conv1 input shared
    const char*  wb   = wp + (size_t)((g * NT + nt) * NCC) * 46080;

    f32x4 acc[OF][4];
#pragma unroll
    for (int o = 0; o < OF; ++o)
#pragma unroll
        for (int p = 0; p < 4; ++p)
#pragma unroll
            for (int r = 0; r < 4; ++r) acc[o][p][r] = 0.f;

    // zero the two pad columns once
    for (int i = t; i < HALO * 2 * 10; i += 256) {
        int rr = i / 20;
        int cp = ((i / 10) & 1) ? 65 : 0;
        int q  = i % 10;
        *reinterpret_cast<s16x4*>(&sA[rr][cp][q * 4]) = s16x4{0, 0, 0, 0};
    }

    for (int cc = 0; cc < NCC; ++cc) {
        // ---- stage sA: HALO rows x 64 cols x 32 ic, b128 per lane
        for (int i = t; i < HALO * 256; i += 256) {
            int q   = i & 3;
            int col = (i >> 2) & 63;
            int row = i >> 8;
            int gy  = r0 - 1 + row;
            s16x4 v = {0, 0, 0, 0};
            if (gy >= 0 && gy < 64) {
                const short* sp = inp + ((gpix + gy * 64 + col) * ICP + cc * 32 + q * 8);
                v = *reinterpret_cast<const s16x4*>(sp);
                s16x4 v2 = *reinterpret_cast<const s16x4*>(sp + 4);
                *reinterpret_cast<s16x4*>(&sA[row][col + 1][q * 8]) = v;
                *reinterpret_cast<s16x4*>(&sA[row][col + 1][q * 8 + 4]) = v2;
            } else {
                *reinterpret_cast<s16x4*>(&sA[row][col + 1][q * 8]) = v;
                *reinterpret_cast<s16x4*>(&sA[row][col + 1][q * 8 + 4]) = v;
            }
        }
        // ---- stage sB: 46080 B via 45 x (64 lanes x 16B) async DMA
        {
            const char* wsrc = wb + (size_t)cc * 46080;
            char* sbb = (char*)&sB[0][0][0];
            for (int r = wave; r < 45; r += 4)
                gl_lds16(wsrc + r * 1024 + lane * 16, sbb + r * 1024);
        }
        __syncthreads();

        // ---- compute: 9 taps
#pragma unroll
        for (int dy = 0; dy < 3; ++dy) {
#pragma unroll
            for (int dx = 0; dx < 3; ++dx) {
                bf16x8 pF[4];
#pragma unroll
                for (int p = 0; p < 4; ++p)
                    pF[p] = *reinterpret_cast<const bf16x8*>(
                        &sA[row_l + dy][p * 16 + l15 + dx][k0]);
                bf16x8 wF[OF];
#pragma unroll
                for (int o = 0; o < OF; ++o)
                    wF[o] = *reinterpret_cast<const bf16x8*>(
                        &sB[ocw + o * 16 + l15][dy * 3 + dx][k0]);
#pragma unroll
                for (int o = 0; o < OF; ++o)
#pragma unroll
                    for (int p = 0; p < 4; ++p)
                        acc[o][p] = __builtin_amdgcn_mfma_f32_16x16x32_bf16(
                            wF[o], pF[p], acc[o][p], 0, 0, 0);
            }
        }
        __syncthreads();
    }

    // ---- epilogue. C/D: m(oc) = quad*4+reg, n(pixel) = l15.
    const int prow = r0 + row_l;
#pragma unroll
    for (int o = 0; o < OF; ++o)
#pragma unroll
        for (int reg = 0; reg < 4; ++reg) {
            const int ocl = ocw + o * 16 + quad * 4 + reg;
            const float bv = bias[g * COUT + nt * 64 + ocl];
            if (PIXMAJ_OUT) {
                const size_t pixbase = ((size_t)g * 4096 + prow * 64);
#pragma unroll
                for (int p = 0; p < 4; ++p) {
                    float v = acc[o][p][reg] + bv;
                    v = v >= 0.f ? v : 0.1f * v;
                    outp[(pixbase + p * 16 + l15) * COUT + nt * 64 + ocl] = f2bs(v);
                }
            } else {
                const size_t base =
                    ((size_t)(g * COUT + nt * 64 + ocl)) * HW + prow * IMG_W;
#pragma unroll
                for (int p = 0; p < 4; ++p) {
                    float v = acc[o][p][reg] + bv;
                    v = v >= 0.f ? v : 0.1f * v;
                    outp[base + p * 16 + l15] = f2bs(v);
                }
            }
        }
}

// ---------------------------------------------------------------------------
// VALU 3x3 conv (proven) — tail convs (conv3: 64->32, conv4: 32->18).
// ---------------------------------------------------------------------------
template<int CIN, int COUT, int OCB, bool LEAKY, bool OUT_F32>
__global__ __launch_bounds__(256)
void conv3x3_kernel(const bf16* __restrict__ in0, const float* __restrict__ wgt,
                    const float* __restrict__ bias, void* __restrict__ outv)
{
    constexpr int ICC = 32;
    constexpr int NCHUNK = CIN / ICC;
    constexpr int ROWS = 8;

    __shared__ __align__(16) bf16 sIn[ICC][ROWS + 2][IMG_W];
    __shared__ __align__(16) float sW[OCB][ICC][9];

    const int t   = threadIdx.x;
    const int pt  = blockIdx.x;
    const int ocb = blockIdx.y;
    const int g   = blockIdx.z;
    const int y0  = pt * ROWS;
    const int oc0 = ocb * OCB;

    const int tr = t >> 6;
    const int x  = t & 63;

    float acc0[OCB], acc1[OCB];
#pragma unroll
    for (int i = 0; i < OCB; ++i) { acc0[i] = 0.f; acc1[i] = 0.f; }

    for (int cc = 0; cc < NCHUNK; ++cc) {
        const int ic0 = cc * ICC;

        constexpr int TOT4 = ICC * (ROWS + 2) * IMG_W / 4;
        for (int i = t; i < TOT4; i += 256) {
            int e   = i * 4;
            int ic  = e / ((ROWS + 2) * IMG_W);
            int rem = e % ((ROWS + 2) * IMG_W);
            int row = rem / IMG_W;
            int col = rem % IMG_W;
            int gy  = y0 - 1 + row;
            bf16 b0, b1c, b2c, b3;
            if (gy >= 0 && gy < 64) {
                const bf16* src = in0 + ((size_t)g * CIN + ic0 + ic) * HW
                                + gy * IMG_W + col;
                b0 = src[0]; b1c = src[1]; b2c = src[2]; b3 = src[3];
            } else {
                b0 = b1c = b2c = b3 = __float2bfloat16(0.f);
            }
            sIn[ic][row][col]     = b0;
            sIn[ic][row][col + 1] = b1c;
            sIn[ic][row][col + 2] = b2c;
            sIn[ic][row][col + 3] = b3;
        }

        constexpr int WTOT = OCB * ICC * 9;
        for (int i = t; i < WTOT; i += 256) {
            int oc  = i / (ICC * 9);
            int rem = i % (ICC * 9);
            int ic  = rem / 9;
            int tap = rem % 9;
            size_t go = ((size_t)(g * COUT + oc0 + oc) * CIN + (ic0 + ic)) * 9 + tap;
            sW[oc][ic][tap] = wgt[go];
        }
        __syncthreads();

        for (int ic = 0; ic < ICC; ++ic) {
            float v0[9], v1[9];
#pragma unroll
            for (int dy = 0; dy < 3; ++dy) {
#pragma unroll
                for (int dx = 0; dx < 3; ++dx) {
                    int cx = x - 1 + dx;
                    bool ok = (cx >= 0) && (cx < 64);
                    int cxc = ok ? cx : 0;
                    float a0 = b2f(sIn[ic][tr + dy][cxc]);
                    float a1 = b2f(sIn[ic][tr + 4 + dy][cxc]);
                    v0[dy * 3 + dx] = ok ? a0 : 0.f;
                    v1[dy * 3 + dx] = ok ? a1 : 0.f;
                }
            }
#pragma unroll
            for (int oc = 0; oc < OCB; ++oc) {
#pragma unroll
                for (int tap = 0; tap < 9; ++tap) {
                    float w = sW[oc][ic][tap];
                    acc0[oc] = fmaf(w, v0[tap], acc0[oc]);
                    acc1[oc] = fmaf(w, v1[tap], acc1[oc]);
                }
            }
        }
        __syncthreads();
    }

    const int p0 = (y0 + tr) * IMG_W + x;
    const int p1 = (y0 + tr + 4) * IMG_W + x;
#pragma unroll
    for (int oc = 0; oc < OCB; ++oc) {
        float b  = bias[g * COUT + oc0 + oc];
        float r0 = acc0[oc] + b;
        float r1 = acc1[oc] + b;
        if (LEAKY) {
            r0 = r0 >= 0.f ? r0 : 0.1f * r0;
            r1 = r1 >= 0.f ? r1 : 0.1f * r1;
        }
        size_t base = (size_t)(g * COUT + oc0 + oc) * HW;
        if (OUT_F32) {
            ((float*)outv)[base + p0] = r0;
            ((float*)outv)[base + p1] = r1;
        } else {
            ((bf16*)outv)[base + p0] = __float2bfloat16(r0);
            ((bf16*)outv)[base + p1] = __float2bfloat16(r1);
        }
    }
}

// ---------------------------------------------------------------------------
// Fused softmax-over-groups + bilinear params + warp + combine (fp32 out).
// gar channels come from inp_t rows (stride 512, first 256 entries).
// ---------------------------------------------------------------------------
__global__ __launch_bounds__(256)
void warp_combine_kernel(const float* __restrict__ oa,
                         const short* __restrict__ inp_t,
                         const float* __restrict__ mask,
                         float* __restrict__ out)
{
    __shared__ __align__(16) float4 sWts[8][6][8];
    __shared__ __align__(16) int4   sIdx[8][6][8];

    const int t = threadIdx.x;

    if (t < 48) {
        int lp = t / 6;
        int k  = t % 6;
        int p  = blockIdx.x * 8 + lp;
        int x  = p & 63, y = p >> 6;

        float l[8];
        float m = -1e30f;
#pragma unroll
        for (int g = 0; g < 8; ++g) {
            l[g] = oa[(size_t)(g * 18 + 12 + k) * HW + p];
            m = fmaxf(m, l[g]);
        }
        float s = 0.f;
#pragma unroll
        for (int g = 0; g < 8; ++g) { l[g] = __expf(l[g] - m); s += l[g]; }
        float inv = 1.f / s;

#pragma unroll
        for (int g = 0; g < 8; ++g) {
            float a  = l[g] * inv;
            float ox = oa[(size_t)(g * 18 + 2 * k)     * HW + p];
            float oy = oa[(size_t)(g * 18 + 2 * k + 1) * HW + p];
            float sx = fminf(fmaxf(((float)x + ox) * (64.f / 63.f) - 0.5f, 0.f), 63.f);
            float sy = fminf(fmaxf(((float)y + oy) * (64.f / 63.f) - 0.5f, 0.f), 63.f);
            float fx0 = floorf(sx), fy0 = floorf(sy);
            int   x0 = (int)fx0,    y0i = (int)fy0;
            float wx = sx - fx0,    wy = sy - fy0;
            int   x1 = min(x0 + 1, 63), y1 = min(y0i + 1, 63);
            sWts[lp][k][g] = make_float4(a * (1.f - wy) * (1.f - wx),
                                         a * (1.f - wy) * wx,
                                         a * wy * (1.f - wx),
                                         a * wy * wx);
            sIdx[lp][k][g] = make_int4(y0i * 64 + x0, y0i * 64 + x1,
                                       y1  * 64 + x0, y1  * 64 + x1);
        }
    }
    __syncthreads();

    const int lp = t >> 5;
    const int p  = blockIdx.x * 8 + lp;
    const int c0 = (t & 31) * 8;

    float acc[8];
#pragma unroll
    for (int j = 0; j < 8; ++j) acc[j] = 0.f;

    for (int g = 0; g < 8; ++g) {
        float4 m0 = *reinterpret_cast<const float4*>(mask + g * 256 + c0);
        float4 m1 = *reinterpret_cast<const float4*>(mask + g * 256 + c0 + 4);
        float mk[8] = {m0.x, m0.y, m0.z, m0.w, m1.x, m1.y, m1.z, m1.w};
#pragma unroll
        for (int k = 0; k < 6; ++k) {
            float4 w  = sWts[lp][k][g];
            int4   id = sIdx[lp][k][g];
            ushort8v v00 = *reinterpret_cast<const ushort8v*>(inp_t + (size_t)id.x * 512 + c0);
            ushort8v v01 = *reinterpret_cast<const ushort8v*>(inp_t + (size_t)id.y * 512 + c0);
            ushort8v v10 = *reinterpret_cast<const ushort8v*>(inp_t + (size_t)id.z * 512 + c0);
            ushort8v v11 = *reinterpret_cast<const ushort8v*>(inp_t + (size_t)id.w * 512 + c0);
#pragma unroll
            for (int j = 0; j < 8; ++j) {
                float sv = w.x * bfbits2f(v00[j]) + w.y * bfbits2f(v01[j])
                         + w.z * bfbits2f(v10[j]) + w.w * bfbits2f(v11[j]);
                acc[j] = fmaf(mk[j], sv, acc[j]);
            }
        }
    }
#pragma unroll
    for (int j = 0; j < 8; ++j)
        out[(size_t)(c0 + j) * HW + p] = acc[j];
}

// ---------------------------------------------------------------------------
// Workspace (peak ~26 MB):
//   [0, 4M)        inp_t  bf16 [4096][512]           (live to the end)
//   [4M, ~15.99M)  W1p    256 blocks x 46080 B       (dead after conv1)
//       reuse: hid2 @4M (4MB), hid3 @8M (2MB), oa @10M (2.25MB fp32)
//   [16M, ~17.4M)  W2p    32 blocks x 46080 B        (dead after conv2)
//   [18M, 26M)     hid1_t bf16 [8][4096][128]        (dead after conv2)
// ---------------------------------------------------------------------------
extern "C" void kernel_launch(void* const* d_in, const int* in_sizes, int n_in,
                              void* d_out, int out_size, void* d_ws, size_t ws_size,
                              hipStream_t stream)
{
    (void)in_sizes; (void)n_in; (void)out_size; (void)ws_size;
    const float* gar  = (const float*)d_in[0];
    const float* cond = (const float*)d_in[1];
    const float* mask = (const float*)d_in[2];
    const float* W1   = (const float*)d_in[3];
    const float* b1   = (const float*)d_in[4];
    const float* W2   = (const float*)d_in[5];
    const float* b2   = (const float*)d_in[6];
    const float* W3   = (const float*)d_in[7];
    const float* b3   = (const float*)d_in[8];
    const float* W4   = (const float*)d_in[9];
    const float* b4   = (const float*)d_in[10];
    float* out = (float*)d_out;

    char* ws = (char*)d_ws;
    short* inp_t  = (short*)(ws);
    char*  W1p    = ws + (4u << 20);
    bf16*  hid2   = (bf16*)(ws + (4u << 20));      // overlays dead W1p
    bf16*  hid3   = (bf16*)(ws + (8u << 20));
    float* oa     = (float*)(ws + (10u << 20));
    char*  W2p    = ws + (16u << 20);
    short* hid1_t = (short*)(ws + (18u << 20));

    pack_input<<<dim3(128, 16), 256, 0, stream>>>(gar, cond, inp_t);
    pack_weights2<512, 128, 2><<<256, 256, 0, stream>>>(W1, W1p);
    pack_weights2<128, 64, 1><<<32, 256, 0, stream>>>(W2, W2p);

    // conv1: ICP=512, COUT=128, ROWS=4 (BM=256), OF=4, NT=2, pixel-major out
    conv_mfma<512, 128, 4, 4, 2, true>
        <<<256, 256, 0, stream>>>(inp_t, W1p, b1, hid1_t);
    // conv2: ICP=128, COUT=64, ROWS=2 (BM=128), OF=2, NT=1, channel-major out
    conv_mfma<128, 64, 2, 2, 1, false>
        <<<256, 256, 0, stream>>>(hid1_t, W2p, b2, (short*)hid2);

    conv3x3_kernel<64, 32, 16, true, false>
        <<<dim3(8, 2, 8), 256, 0, stream>>>(hid2, W3, b3, hid3);
    conv3x3_kernel<32, 18, 18, false, true>
        <<<dim3(8, 1, 8), 256, 0, stream>>>(hid3, W4, b4, oa);

    warp_combine_kernel<<<512, 256, 0, stream>>>(oa, inp_t, mask, out);
}

// Round 7
// 280.482 us; speedup vs baseline: 6.8033x; 1.5574x over previous
//
#include <hip/hip_runtime.h>
#include <hip/hip_bf16.h>

typedef __hip_bfloat16 bf16;
typedef unsigned short ushort8v __attribute__((ext_vector_type(8)));
typedef short  s16x4  __attribute__((ext_vector_type(4)));
typedef short  bf16x8 __attribute__((ext_vector_type(8)));   // 8 bf16 (4 VGPRs)
typedef float  f32x4  __attribute__((ext_vector_type(4)));

#define HW 4096
#define IMG_W 64

__device__ __forceinline__ float b2f(bf16 v) { return __bfloat162float(v); }
__device__ __forceinline__ float bfbits2f(unsigned short u) {
    return __uint_as_float(((unsigned int)u) << 16);
}
__device__ __forceinline__ short f2bs(float f) {
    bf16 h = __float2bfloat16(f);
    return *reinterpret_cast<short*>(&h);
}

// async global->LDS, 16B per lane (wave-uniform LDS base + lane*16 scatter).
__device__ __forceinline__ void gl_lds16(const void* g, void* s) {
    __builtin_amdgcn_global_load_lds(
        (const __attribute__((address_space(1))) unsigned int*)g,
        (__attribute__((address_space(3))) unsigned int*)s, 16, 0, 0);
}

// ---------------------------------------------------------------------------
// pack_input: concat(gar,cond) fp32 [512][4096] -> inp_t bf16 [4096][512]
// (pixel-major). inp_t[:, 0:256] doubles as gar_t for the warp kernel.
// ---------------------------------------------------------------------------
__global__ __launch_bounds__(256)
void pack_input(const float* __restrict__ gar, const float* __restrict__ cond,
                short* __restrict__ outp)
{
    __shared__ __align__(16) float tile[32][33];
    int bx = blockIdx.x;               // px tile (128)
    int by = blockIdx.y;               // ch tile (16)
    int tx = threadIdx.x & 31;
    int ty = threadIdx.x >> 5;
#pragma unroll
    for (int i = 0; i < 4; ++i) {
        int c = by * 32 + ty + i * 8;
        const float* src = (c < 256) ? (gar + (size_t)c * HW)
                                     : (cond + (size_t)(c - 256) * HW);
        tile[ty + i * 8][tx] = src[bx * 32 + tx];
    }
    __syncthreads();
#pragma unroll
    for (int i = 0; i < 4; ++i) {
        int p = bx * 32 + ty + i * 8;
        outp[(size_t)p * 512 + by * 32 + tx] = f2bs(tile[tx][ty + i * 8]);
    }
}

// ---------------------------------------------------------------------------
// pack_w: W fp32 [G][CREAL][CIN][3][3] -> bf16 blocks
// [g][nt][cc][BN oc][9 tap][40 ic] (ic: 32 payload + 8 zero pad; oc zero-pad
// beyond CREAL), padded to BLKB = ceil(BN*720/1024)*1024 bytes so the conv
// kernel stages one block with BLKB/1024 wave-wide global_load_lds rows.
// ---------------------------------------------------------------------------
template<int CIN, int CREAL, int BN, int NT>
__global__ __launch_bounds__(256)
void pack_w(const float* __restrict__ wgt, char* __restrict__ wp)
{
    constexpr int NCC  = CIN / 32;
    constexpr int BLKB = ((BN * 720 + 1023) / 1024) * 1024;
    __shared__ __align__(16) short sT[BN][9][40];

    const int t  = threadIdx.x;
    const int bx = blockIdx.x;                 // g*NT*NCC + nt*NCC + cc
    const int cc = bx % NCC;
    const int nt = (bx / NCC) % NT;
    const int g  = bx / (NT * NCC);

    for (int i = t; i < BN * 90; i += 256)     // zero all (covers pads)
        *reinterpret_cast<s16x4*>(&sT[0][0][0] + (size_t)i * 4) = s16x4{0, 0, 0, 0};
    __syncthreads();

    int ocmax = CREAL - nt * BN; if (ocmax > BN) ocmax = BN;
    const size_t base = ((size_t)(g * CREAL + nt * BN) * CIN + cc * 32) * 9;
    for (int i = t; i < ocmax * 288; i += 256) {
        int oc = i / 288;
        int r  = i % 288;                      // ic*9 + tap
        int ic = r / 9, tap = r % 9;
        sT[oc][tap][ic] = f2bs(wgt[base + (size_t)oc * CIN * 9 + r]);
    }
    __syncthreads();

    const char* src = (const char*)&sT[0][0][0];
    char* dst = wp + (size_t)bx * BLKB;
    for (int i = t; i < BLKB / 8; i += 256) {
        s16x4 v = (i * 8 < BN * 720)
            ? *reinterpret_cast<const s16x4*>(src + (size_t)i * 8)
            : s16x4{0, 0, 0, 0};
        *reinterpret_cast<s16x4*>(dst + (size_t)i * 8) = v;
    }
}

// ---------------------------------------------------------------------------
// Implicit-GEMM 3x3 SAME conv, bf16 MFMA 16x16x32.
// Input pixel-major bf16 [g?][4096 px][ICP]; weights prepacked (pack_w).
// Tile: ROWS image rows (BM=ROWS*64 px) x BN out-chans. 4 waves:
//   ROWS=4: wave -> row, OF = BN/16 o-frags each
//   ROWS=2: wave -> (row, BN/2-oc half), OF = BN/32 o-frags each
// Per cc-phase: stage sA (b128 VGPR path) + sB (global_load_lds), 9 taps,
// OF*4 MFMA per tap per wave.
// CREAL: real out-chans (<= NT*BN; oc pad computed but not stored).
// ---------------------------------------------------------------------------
template<int ICP, int CREAL, int BN, int ROWS, int OF, int NT,
         bool PIXMAJ_OUT, bool LEAKY, bool OUT_F32>
__global__ __launch_bounds__(256)
void conv_mfma(const short* __restrict__ inp, const char* __restrict__ wp,
               const float* __restrict__ bias, void* __restrict__ outv)
{
    constexpr int NCC  = ICP / 32;
    constexpr int HALO = ROWS + 2;
    constexpr int NPT  = 4096 / (ROWS * 64);
    constexpr int BLKB = ((BN * 720 + 1023) / 1024) * 1024;
    constexpr int RNDS = BLKB / 1024;

    __shared__ __align__(16) short sA[HALO][66][40];
    __shared__ __align__(16) char  sBraw[BLKB];
    short (*sB)[9][40] = reinterpret_cast<short(*)[9][40]>(sBraw);

    const int b  = blockIdx.x;
    const int g  = b & 7;                     // XCD swizzle: group per XCD
    const int r_ = b >> 3;
    const int pt = r_ % NPT;
    const int nt = r_ / NPT;
    const int r0 = pt * ROWS;

    const int t    = threadIdx.x;
    const int wave = t >> 6, lane = t & 63;
    const int l15  = lane & 15, quad = lane >> 4;
    const int row_l = (ROWS == 4) ? wave : (wave & 1);
    const int ocw   = (ROWS == 4) ? 0 : (wave >> 1) * (BN / 2);
    const int k0    = quad * 8;

    const size_t gpix = (ICP == 512) ? 0 : ((size_t)g * 4096);
    const char*  wb   = wp + (size_t)((g * NT + nt) * NCC) * BLKB;

    f32x4 acc[OF][4];
#pragma unroll
    for (int o = 0; o < OF; ++o)
#pragma unroll
        for (int p = 0; p < 4; ++p)
#pragma unroll
            for (int r = 0; r < 4; ++r) acc[o][p][r] = 0.f;

    // zero the two x-pad columns once
    for (int i = t; i < HALO * 2 * 10; i += 256) {
        int rr = i / 20;
        int cp = ((i / 10) & 1) ? 65 : 0;
        int q  = i % 10;
        *reinterpret_cast<s16x4*>(&sA[rr][cp][q * 4]) = s16x4{0, 0, 0, 0};
    }

    for (int cc = 0; cc < NCC; ++cc) {
        // ---- stage sA: HALO rows x 64 cols x 32 ic
        for (int i = t; i < HALO * 256; i += 256) {
            int q   = i & 3;
            int col = (i >> 2) & 63;
            int row = i >> 8;
            int gy  = r0 - 1 + row;
            if (gy >= 0 && gy < 64) {
                const short* sp = inp + ((gpix + gy * 64 + col) * ICP + cc * 32 + q * 8);
                s16x4 v  = *reinterpret_cast<const s16x4*>(sp);
                s16x4 v2 = *reinterpret_cast<const s16x4*>(sp + 4);
                *reinterpret_cast<s16x4*>(&sA[row][col + 1][q * 8])     = v;
                *reinterpret_cast<s16x4*>(&sA[row][col + 1][q * 8 + 4]) = v2;
            } else {
                s16x4 z = {0, 0, 0, 0};
                *reinterpret_cast<s16x4*>(&sA[row][col + 1][q * 8])     = z;
                *reinterpret_cast<s16x4*>(&sA[row][col + 1][q * 8 + 4]) = z;
            }
        }
        // ---- stage sB via wave-wide async DMA rows of 1024 B
        {
            const char* wsrc = wb + (size_t)cc * BLKB;
            for (int r = wave; r < RNDS; r += 4)
                gl_lds16(wsrc + r * 1024 + lane * 16, sBraw + r * 1024);
        }
        __syncthreads();

        // ---- compute: 9 taps
#pragma unroll
        for (int dy = 0; dy < 3; ++dy) {
#pragma unroll
            for (int dx = 0; dx < 3; ++dx) {
                bf16x8 pF[4];
#pragma unroll
                for (int p = 0; p < 4; ++p)
                    pF[p] = *reinterpret_cast<const bf16x8*>(
                        &sA[row_l + dy][p * 16 + l15 + dx][k0]);
                bf16x8 wF[OF];
#pragma unroll
                for (int o = 0; o < OF; ++o)
                    wF[o] = *reinterpret_cast<const bf16x8*>(
                        &sB[ocw + o * 16 + l15][dy * 3 + dx][k0]);
#pragma unroll
                for (int o = 0; o < OF; ++o)
#pragma unroll
                    for (int p = 0; p < 4; ++p)
                        acc[o][p] = __builtin_amdgcn_mfma_f32_16x16x32_bf16(
                            wF[o], pF[p], acc[o][p], 0, 0, 0);
            }
        }
        __syncthreads();
    }

    // ---- epilogue. C/D: m(oc) = quad*4+reg, n(pixel) = l15.
    const int prow = r0 + row_l;
#pragma unroll
    for (int o = 0; o < OF; ++o)
#pragma unroll
        for (int reg = 0; reg < 4; ++reg) {
            const int ocl = ocw + o * 16 + quad * 4 + reg;
            const int ocg = nt * BN + ocl;
            if (ocg < CREAL) {
                const float bv = bias[g * CREAL + ocg];
                if (PIXMAJ_OUT) {
                    short* outp = (short*)outv;
                    const size_t pixbase = ((size_t)g * 4096 + prow * 64);
#pragma unroll
                    for (int p = 0; p < 4; ++p) {
                        float v = acc[o][p][reg] + bv;
                        if (LEAKY) v = v >= 0.f ? v : 0.1f * v;
                        outp[(pixbase + p * 16 + l15) * (NT * BN) + ocg] = f2bs(v);
                    }
                } else if (OUT_F32) {
                    float* outp = (float*)outv;
                    const size_t base = ((size_t)(g * CREAL + ocg)) * HW + prow * IMG_W;
#pragma unroll
                    for (int p = 0; p < 4; ++p) {
                        float v = acc[o][p][reg] + bv;
                        if (LEAKY) v = v >= 0.f ? v : 0.1f * v;
                        outp[base + p * 16 + l15] = v;
                    }
                } else {
                    short* outp = (short*)outv;
                    const size_t base = ((size_t)(g * CREAL + ocg)) * HW + prow * IMG_W;
#pragma unroll
                    for (int p = 0; p < 4; ++p) {
                        float v = acc[o][p][reg] + bv;
                        if (LEAKY) v = v >= 0.f ? v : 0.1f * v;
                        outp[base + p * 16 + l15] = f2bs(v);
                    }
                }
            }
        }
}

// ---------------------------------------------------------------------------
// Fused softmax-over-groups + bilinear params + warp + combine (fp32 out).
// gar channels come from inp_t rows (stride 512, first 256 entries).
// ---------------------------------------------------------------------------
__global__ __launch_bounds__(256)
void warp_combine_kernel(const float* __restrict__ oa,
                         const short* __restrict__ inp_t,
                         const float* __restrict__ mask,
                         float* __restrict__ out)
{
    __shared__ __align__(16) float4 sWts[8][6][8];
    __shared__ __align__(16) int4   sIdx[8][6][8];

    const int t = threadIdx.x;

    if (t < 48) {
        int lp = t / 6;
        int k  = t % 6;
        int p  = blockIdx.x * 8 + lp;
        int x  = p & 63, y = p >> 6;

        float l[8];
        float m = -1e30f;
#pragma unroll
        for (int g = 0; g < 8; ++g) {
            l[g] = oa[(size_t)(g * 18 + 12 + k) * HW + p];
            m = fmaxf(m, l[g]);
        }
        float s = 0.f;
#pragma unroll
        for (int g = 0; g < 8; ++g) { l[g] = __expf(l[g] - m); s += l[g]; }
        float inv = 1.f / s;

#pragma unroll
        for (int g = 0; g < 8; ++g) {
            float a  = l[g] * inv;
            float ox = oa[(size_t)(g * 18 + 2 * k)     * HW + p];
            float oy = oa[(size_t)(g * 18 + 2 * k + 1) * HW + p];
            float sx = fminf(fmaxf(((float)x + ox) * (64.f / 63.f) - 0.5f, 0.f), 63.f);
            float sy = fminf(fmaxf(((float)y + oy) * (64.f / 63.f) - 0.5f, 0.f), 63.f);
            float fx0 = floorf(sx), fy0 = floorf(sy);
            int   x0 = (int)fx0,    y0i = (int)fy0;
            float wx = sx - fx0,    wy = sy - fy0;
            int   x1 = min(x0 + 1, 63), y1 = min(y0i + 1, 63);
            sWts[lp][k][g] = make_float4(a * (1.f - wy) * (1.f - wx),
                                         a * (1.f - wy) * wx,
                                         a * wy * (1.f - wx),
                                         a * wy * wx);
            sIdx[lp][k][g] = make_int4(y0i * 64 + x0, y0i * 64 + x1,
                                       y1  * 64 + x0, y1  * 64 + x1);
        }
    }
    __syncthreads();

    const int lp = t >> 5;
    const int p  = blockIdx.x * 8 + lp;
    const int c0 = (t & 31) * 8;

    float acc[8];
#pragma unroll
    for (int j = 0; j < 8; ++j) acc[j] = 0.f;

    for (int g = 0; g < 8; ++g) {
        float4 m0 = *reinterpret_cast<const float4*>(mask + g * 256 + c0);
        float4 m1 = *reinterpret_cast<const float4*>(mask + g * 256 + c0 + 4);
        float mk[8] = {m0.x, m0.y, m0.z, m0.w, m1.x, m1.y, m1.z, m1.w};
#pragma unroll
        for (int k = 0; k < 6; ++k) {
            float4 w  = sWts[lp][k][g];
            int4   id = sIdx[lp][k][g];
            ushort8v v00 = *reinterpret_cast<const ushort8v*>(inp_t + (size_t)id.x * 512 + c0);
            ushort8v v01 = *reinterpret_cast<const ushort8v*>(inp_t + (size_t)id.y * 512 + c0);
            ushort8v v10 = *reinterpret_cast<const ushort8v*>(inp_t + (size_t)id.z * 512 + c0);
            ushort8v v11 = *reinterpret_cast<const ushort8v*>(inp_t + (size_t)id.w * 512 + c0);
#pragma unroll
            for (int j = 0; j < 8; ++j) {
                float sv = w.x * bfbits2f(v00[j]) + w.y * bfbits2f(v01[j])
                         + w.z * bfbits2f(v10[j]) + w.w * bfbits2f(v11[j]);
                acc[j] = fmaf(mk[j], sv, acc[j]);
            }
        }
    }
#pragma unroll
    for (int j = 0; j < 8; ++j)
        out[(size_t)(c0 + j) * HW + p] = acc[j];
}

// ---------------------------------------------------------------------------
// Workspace (peak ~26.5 MB):
//   [0, 4M)        inp_t  bf16 [4096][512]              (live to end)
//   [4M, 15.25M)   W1p    256 x 46080 B                 (dead after conv1)
//       reuse:     hid2_t @4M  bf16 [8][4096][64] (4MB)
//                  hid3_t @8M  bf16 [8][4096][32] (2MB)
//                  oa     @10.5M fp32 [8][18][4096] (2.25MB)
//   [16M, 17.5M)   W2p    32 x 46080 B
//   [17.5M, 18M)   W3p    16 x 23552 B
//   [18M, 18.5M)   W4p     8 x 23552 B
//   [18.5M, 26.5M) hid1_t bf16 [8][4096][128]           (dead after conv2)
// ---------------------------------------------------------------------------
extern "C" void kernel_launch(void* const* d_in, const int* in_sizes, int n_in,
                              void* d_out, int out_size, void* d_ws, size_t ws_size,
                              hipStream_t stream)
{
    (void)in_sizes; (void)n_in; (void)out_size; (void)ws_size;
    const float* gar  = (const float*)d_in[0];
    const float* cond = (const float*)d_in[1];
    const float* mask = (const float*)d_in[2];
    const float* W1   = (const float*)d_in[3];
    const float* b1   = (const float*)d_in[4];
    const float* W2   = (const float*)d_in[5];
    const float* b2   = (const float*)d_in[6];
    const float* W3   = (const float*)d_in[7];
    const float* b3   = (const float*)d_in[8];
    const float* W4   = (const float*)d_in[9];
    const float* b4   = (const float*)d_in[10];
    float* out = (float*)d_out;

    char* ws = (char*)d_ws;
    short* inp_t  = (short*)(ws);
    char*  W1p    = ws + (4u << 20);
    short* hid2_t = (short*)(ws + (4u << 20));          // overlays dead W1p
    short* hid3_t = (short*)(ws + (8u << 20));          // overlays dead W1p
    float* oa     = (float*)(ws + (10u << 20) + (512u << 10));
    char*  W2p    = ws + (16u << 20);
    char*  W3p    = ws + (17u << 20) + (512u << 10);
    char*  W4p    = ws + (18u << 20);
    short* hid1_t = (short*)(ws + (18u << 20) + (512u << 10));

    pack_input<<<dim3(128, 16), 256, 0, stream>>>(gar, cond, inp_t);
    pack_w<512, 128, 64, 2><<<256, 256, 0, stream>>>(W1, W1p);
    pack_w<128,  64, 64, 1><<< 32, 256, 0, stream>>>(W2, W2p);
    pack_w< 64,  32, 32, 1><<< 16, 256, 0, stream>>>(W3, W3p);
    pack_w< 32,  18, 32, 1><<<  8, 256, 0, stream>>>(W4, W4p);

    // conv1: 512->128, ROWS=4, BN=64, OF=4, NT=2, pixel-major out, leaky
    conv_mfma<512, 128, 64, 4, 4, 2, true, true, false>
        <<<256, 256, 0, stream>>>(inp_t, W1p, b1, hid1_t);
    // conv2: 128->64, ROWS=2, BN=64, OF=2, NT=1, pixel-major out, leaky
    conv_mfma<128, 64, 64, 2, 2, 1, true, true, false>
        <<<256, 256, 0, stream>>>(hid1_t, W2p, b2, hid2_t);
    // conv3: 64->32, ROWS=4, BN=32, OF=2, NT=1, pixel-major out, leaky
    conv_mfma<64, 32, 32, 4, 2, 1, true, true, false>
        <<<128, 256, 0, stream>>>(hid2_t, W3p, b3, hid3_t);
    // conv4: 32->18 (pad 32), ROWS=4, BN=32, OF=2, NT=1, ch-major fp32, linear
    conv_mfma<32, 18, 32, 4, 2, 1, false, false, true>
        <<<128, 256, 0, stream>>>(hid3_t, W4p, b4, oa);

    warp_combine_kernel<<<512, 256, 0, stream>>>(oa, inp_t, mask, out);
}

// Round 8
// 254.769 us; speedup vs baseline: 7.4899x; 1.1009x over previous
//
#include <hip/hip_runtime.h>
#include <hip/hip_bf16.h>

typedef __hip_bfloat16 bf16;
typedef unsigned short ushort8v __attribute__((ext_vector_type(8)));
typedef short  s16x4  __attribute__((ext_vector_type(4)));
typedef short  bf16x8 __attribute__((ext_vector_type(8)));   // 8 bf16 (4 VGPRs)
typedef float  f32x4  __attribute__((ext_vector_type(4)));

#define HW 4096
#define IMG_W 64

__device__ __forceinline__ float b2f(bf16 v) { return __bfloat162float(v); }
__device__ __forceinline__ float bfbits2f(unsigned short u) {
    return __uint_as_float(((unsigned int)u) << 16);
}
__device__ __forceinline__ short f2bs(float f) {
    bf16 h = __float2bfloat16(f);
    return *reinterpret_cast<short*>(&h);
}

// async global->LDS, 16B per lane (wave-uniform LDS base + lane*16 scatter).
__device__ __forceinline__ void gl_lds16(const void* g, void* s) {
    __builtin_amdgcn_global_load_lds(
        (const __attribute__((address_space(1))) unsigned int*)g,
        (__attribute__((address_space(3))) unsigned int*)s, 16, 0, 0);
}

// ---------------------------------------------------------------------------
// pack_input: concat(gar,cond) fp32 [512][4096] -> inp_t bf16 [4096][512]
// (pixel-major). inp_t[:, 0:256] doubles as gar_t for the warp kernel.
// ---------------------------------------------------------------------------
__global__ __launch_bounds__(256)
void pack_input(const float* __restrict__ gar, const float* __restrict__ cond,
                short* __restrict__ outp)
{
    __shared__ __align__(16) float tile[32][33];
    int bx = blockIdx.x;               // px tile (128)
    int by = blockIdx.y;               // ch tile (16)
    int tx = threadIdx.x & 31;
    int ty = threadIdx.x >> 5;
#pragma unroll
    for (int i = 0; i < 4; ++i) {
        int c = by * 32 + ty + i * 8;
        const float* src = (c < 256) ? (gar + (size_t)c * HW)
                                     : (cond + (size_t)(c - 256) * HW);
        tile[ty + i * 8][tx] = src[bx * 32 + tx];
    }
    __syncthreads();
#pragma unroll
    for (int i = 0; i < 4; ++i) {
        int p = bx * 32 + ty + i * 8;
        outp[(size_t)p * 512 + by * 32 + tx] = f2bs(tile[tx][ty + i * 8]);
    }
}

// ---------------------------------------------------------------------------
// pack_w: W fp32 [G][CREAL][CIN][3][3] -> bf16 blocks
// [g][nt][cc][BN oc][9 tap][40 ic] (ic: 32 payload + 8 zero pad; oc zero-pad
// beyond CREAL), padded to BLKB = ceil(BN*720/1024)*1024 bytes so the conv
// kernel stages one block with BLKB/1024 wave-wide global_load_lds rows.
// ---------------------------------------------------------------------------
template<int CIN, int CREAL, int BN, int NT>
__global__ __launch_bounds__(256)
void pack_w(const float* __restrict__ wgt, char* __restrict__ wp)
{
    constexpr int NCC  = CIN / 32;
    constexpr int BLKB = ((BN * 720 + 1023) / 1024) * 1024;
    __shared__ __align__(16) short sT[BN][9][40];

    const int t  = threadIdx.x;
    const int bx = blockIdx.x;                 // g*NT*NCC + nt*NCC + cc
    const int cc = bx % NCC;
    const int nt = (bx / NCC) % NT;
    const int g  = bx / (NT * NCC);

    for (int i = t; i < BN * 90; i += 256)     // zero all (covers pads)
        *reinterpret_cast<s16x4*>(&sT[0][0][0] + (size_t)i * 4) = s16x4{0, 0, 0, 0};
    __syncthreads();

    int ocmax = CREAL - nt * BN; if (ocmax > BN) ocmax = BN;
    const size_t base = ((size_t)(g * CREAL + nt * BN) * CIN + cc * 32) * 9;
    for (int i = t; i < ocmax * 288; i += 256) {
        int oc = i / 288;
        int r  = i % 288;                      // ic*9 + tap
        int ic = r / 9, tap = r % 9;
        sT[oc][tap][ic] = f2bs(wgt[base + (size_t)oc * CIN * 9 + r]);
    }
    __syncthreads();

    const char* src = (const char*)&sT[0][0][0];
    char* dst = wp + (size_t)bx * BLKB;
    for (int i = t; i < BLKB / 8; i += 256) {
        s16x4 v = (i * 8 < BN * 720)
            ? *reinterpret_cast<const s16x4*>(src + (size_t)i * 8)
            : s16x4{0, 0, 0, 0};
        *reinterpret_cast<s16x4*>(dst + (size_t)i * 8) = v;
    }
}

// ---------------------------------------------------------------------------
// Implicit-GEMM 3x3 SAME conv, bf16 MFMA 16x16x32, software-pipelined.
// Input pixel-major bf16 [g?][4096 px][ICP]; weights prepacked (pack_w).
// Tile: ROWS image rows (BM=ROWS*64 px) x BN out-chans, 4 waves.
// Pipeline per cc-phase (NCC>1): top barrier -> issue sB DMA(cc+1, alt buf)
// + sA global prefetch(cc+1) into regs -> compute(cc) -> mid barrier ->
// ds_write sA regs. Staging latency hides behind the LDS-read-bound compute.
// sA staged as single b128 stores (bank-start uniform over 8 classes).
// ---------------------------------------------------------------------------
template<int ICP, int CREAL, int BN, int ROWS, int OF, int NT,
         bool PIXMAJ_OUT, bool LEAKY, bool OUT_F32>
__global__ __launch_bounds__(256)
void conv_mfma(const short* __restrict__ inp, const char* __restrict__ wp,
               const float* __restrict__ bias, void* __restrict__ outv)
{
    constexpr int NCC  = ICP / 32;
    constexpr int HALO = ROWS + 2;
    constexpr int NPT  = 4096 / (ROWS * 64);
    constexpr int BLKB = ((BN * 720 + 1023) / 1024) * 1024;
    constexpr int RNDS = BLKB / 1024;
    constexpr int NBUF = (NCC > 1) ? 2 : 1;

    __shared__ __align__(16) short sA[HALO][66][40];
    __shared__ __align__(16) char  sBraw[NBUF][BLKB];

    const int b  = blockIdx.x;
    const int g  = b & 7;                     // XCD swizzle: group per XCD
    const int r_ = b >> 3;
    const int pt = r_ % NPT;
    const int nt = r_ / NPT;
    const int r0 = pt * ROWS;

    const int t    = threadIdx.x;
    const int wave = t >> 6, lane = t & 63;
    const int l15  = lane & 15, quad = lane >> 4;
    const int row_l = (ROWS == 4) ? wave : (wave & 1);
    const int ocw   = (ROWS == 4) ? 0 : (wave >> 1) * (BN / 2);
    const int k0    = quad * 8;

    const size_t gpix = (ICP == 512) ? 0 : ((size_t)g * 4096);
    const char*  wb   = wp + (size_t)((g * NT + nt) * NCC) * BLKB;

    // per-thread sA staging slot: 16B unit (q-quarter of 32 ic) per halo row
    const int aq   = t & 3;
    const int acol = (t >> 2) & 63;

    bf16x8 pre[HALO];

    auto stageA_load = [&](int cc) {
#pragma unroll
        for (int j = 0; j < HALO; ++j) {
            int gy = r0 - 1 + j;
            bf16x8 v = {0, 0, 0, 0, 0, 0, 0, 0};
            if (gy >= 0 && gy < 64)
                v = *reinterpret_cast<const bf16x8*>(
                    inp + ((gpix + gy * 64 + acol) * ICP + cc * 32 + aq * 8));
            pre[j] = v;
        }
    };
    auto stageA_write = [&]() {
#pragma unroll
        for (int j = 0; j < HALO; ++j)
            *reinterpret_cast<bf16x8*>(&sA[j][acol + 1][aq * 8]) = pre[j];
    };
    auto stageB = [&](int cc) {
        const char* wsrc = wb + (size_t)cc * BLKB;
        char* sbb = (char*)sBraw[cc & (NBUF - 1)];
        for (int r = wave; r < RNDS; r += 4)
            gl_lds16(wsrc + r * 1024 + lane * 16, sbb + r * 1024);
    };

    f32x4 acc[OF][4];
#pragma unroll
    for (int o = 0; o < OF; ++o)
#pragma unroll
        for (int p = 0; p < 4; ++p)
#pragma unroll
            for (int r = 0; r < 4; ++r) acc[o][p][r] = 0.f;

    // zero the two x-pad columns once (5 b128 units per (row,col))
    for (int i = t; i < HALO * 2 * 5; i += 256) {
        int rr = i / 10;
        int cp = ((i / 5) & 1) ? 65 : 0;
        int q  = i % 5;
        bf16x8 z = {0, 0, 0, 0, 0, 0, 0, 0};
        *reinterpret_cast<bf16x8*>(&sA[rr][cp][q * 8]) = z;
    }

    // prologue: stage phase 0
    stageB(0);
    stageA_load(0);
    stageA_write();

    for (int cc = 0; cc < NCC; ++cc) {
        __syncthreads();           // sA(cc) written, sB(cc) DMA drained
        if constexpr (NBUF == 2) {
            if (cc + 1 < NCC) {
                stageB(cc + 1);        // DMA into alternate buffer
                stageA_load(cc + 1);   // global -> regs, no LDS touch
            }
        }
        const short (*sB)[9][40] =
            reinterpret_cast<const short(*)[9][40]>(sBraw[cc & (NBUF - 1)]);

#pragma unroll
        for (int dy = 0; dy < 3; ++dy) {
#pragma unroll
            for (int dx = 0; dx < 3; ++dx) {
                bf16x8 pF[4];
#pragma unroll
                for (int p = 0; p < 4; ++p)
                    pF[p] = *reinterpret_cast<const bf16x8*>(
                        &sA[row_l + dy][p * 16 + l15 + dx][k0]);
                bf16x8 wF[OF];
#pragma unroll
                for (int o = 0; o < OF; ++o)
                    wF[o] = *reinterpret_cast<const bf16x8*>(
                        &sB[ocw + o * 16 + l15][dy * 3 + dx][k0]);
#pragma unroll
                for (int o = 0; o < OF; ++o)
#pragma unroll
                    for (int p = 0; p < 4; ++p)
                        acc[o][p] = __builtin_amdgcn_mfma_f32_16x16x32_bf16(
                            wF[o], pF[p], acc[o][p], 0, 0, 0);
            }
        }
        __syncthreads();           // all reads of sA(cc) done
        if (cc + 1 < NCC) stageA_write();
    }

    // ---- epilogue. C/D: m(oc) = quad*4+reg, n(pixel) = l15.
    const int prow = r0 + row_l;
#pragma unroll
    for (int o = 0; o < OF; ++o)
#pragma unroll
        for (int reg = 0; reg < 4; ++reg) {
            const int ocl = ocw + o * 16 + quad * 4 + reg;
            const int ocg = nt * BN + ocl;
            if (ocg < CREAL) {
                const float bv = bias[g * CREAL + ocg];
                if (PIXMAJ_OUT) {
                    short* outp = (short*)outv;
                    const size_t pixbase = ((size_t)g * 4096 + prow * 64);
#pragma unroll
                    for (int p = 0; p < 4; ++p) {
                        float v = acc[o][p][reg] + bv;
                        if (LEAKY) v = v >= 0.f ? v : 0.1f * v;
                        outp[(pixbase + p * 16 + l15) * (NT * BN) + ocg] = f2bs(v);
                    }
                } else if (OUT_F32) {
                    float* outp = (float*)outv;
                    const size_t base = ((size_t)(g * CREAL + ocg)) * HW + prow * IMG_W;
#pragma unroll
                    for (int p = 0; p < 4; ++p) {
                        float v = acc[o][p][reg] + bv;
                        if (LEAKY) v = v >= 0.f ? v : 0.1f * v;
                        outp[base + p * 16 + l15] = v;
                    }
                } else {
                    short* outp = (short*)outv;
                    const size_t base = ((size_t)(g * CREAL + ocg)) * HW + prow * IMG_W;
#pragma unroll
                    for (int p = 0; p < 4; ++p) {
                        float v = acc[o][p][reg] + bv;
                        if (LEAKY) v = v >= 0.f ? v : 0.1f * v;
                        outp[base + p * 16 + l15] = f2bs(v);
                    }
                }
            }
        }
}

// ---------------------------------------------------------------------------
// Fused softmax-over-groups + bilinear params + warp + combine (fp32 out).
// gar channels come from inp_t rows (stride 512, first 256 entries).
// ---------------------------------------------------------------------------
__global__ __launch_bounds__(256)
void warp_combine_kernel(const float* __restrict__ oa,
                         const short* __restrict__ inp_t,
                         const float* __restrict__ mask,
                         float* __restrict__ out)
{
    __shared__ __align__(16) float4 sWts[8][6][8];
    __shared__ __align__(16) int4   sIdx[8][6][8];

    const int t = threadIdx.x;

    if (t < 48) {
        int lp = t / 6;
        int k  = t % 6;
        int p  = blockIdx.x * 8 + lp;
        int x  = p & 63, y = p >> 6;

        float l[8];
        float m = -1e30f;
#pragma unroll
        for (int g = 0; g < 8; ++g) {
            l[g] = oa[(size_t)(g * 18 + 12 + k) * HW + p];
            m = fmaxf(m, l[g]);
        }
        float s = 0.f;
#pragma unroll
        for (int g = 0; g < 8; ++g) { l[g] = __expf(l[g] - m); s += l[g]; }
        float inv = 1.f / s;

#pragma unroll
        for (int g = 0; g < 8; ++g) {
            float a  = l[g] * inv;
            float ox = oa[(size_t)(g * 18 + 2 * k)     * HW + p];
            float oy = oa[(size_t)(g * 18 + 2 * k + 1) * HW + p];
            float sx = fminf(fmaxf(((float)x + ox) * (64.f / 63.f) - 0.5f, 0.f), 63.f);
            float sy = fminf(fmaxf(((float)y + oy) * (64.f / 63.f) - 0.5f, 0.f), 63.f);
            float fx0 = floorf(sx), fy0 = floorf(sy);
            int   x0 = (int)fx0,    y0i = (int)fy0;
            float wx = sx - fx0,    wy = sy - fy0;
            int   x1 = min(x0 + 1, 63), y1 = min(y0i + 1, 63);
            sWts[lp][k][g] = make_float4(a * (1.f - wy) * (1.f - wx),
                                         a * (1.f - wy) * wx,
                                         a * wy * (1.f - wx),
                                         a * wy * wx);
            sIdx[lp][k][g] = make_int4(y0i * 64 + x0, y0i * 64 + x1,
                                       y1  * 64 + x0, y1  * 64 + x1);
        }
    }
    __syncthreads();

    const int lp = t >> 5;
    const int p  = blockIdx.x * 8 + lp;
    const int c0 = (t & 31) * 8;

    float acc[8];
#pragma unroll
    for (int j = 0; j < 8; ++j) acc[j] = 0.f;

    for (int g = 0; g < 8; ++g) {
        float4 m0 = *reinterpret_cast<const float4*>(mask + g * 256 + c0);
        float4 m1 = *reinterpret_cast<const float4*>(mask + g * 256 + c0 + 4);
        float mk[8] = {m0.x, m0.y, m0.z, m0.w, m1.x, m1.y, m1.z, m1.w};
#pragma unroll
        for (int k = 0; k < 6; ++k) {
            float4 w  = sWts[lp][k][g];
            int4   id = sIdx[lp][k][g];
            ushort8v v00 = *reinterpret_cast<const ushort8v*>(inp_t + (size_t)id.x * 512 + c0);
            ushort8v v01 = *reinterpret_cast<const ushort8v*>(inp_t + (size_t)id.y * 512 + c0);
            ushort8v v10 = *reinterpret_cast<const ushort8v*>(inp_t + (size_t)id.z * 512 + c0);
            ushort8v v11 = *reinterpret_cast<const ushort8v*>(inp_t + (size_t)id.w * 512 + c0);
#pragma unroll
            for (int j = 0; j < 8; ++j) {
                float sv = w.x * bfbits2f(v00[j]) + w.y * bfbits2f(v01[j])
                         + w.z * bfbits2f(v10[j]) + w.w * bfbits2f(v11[j]);
                acc[j] = fmaf(mk[j], sv, acc[j]);
            }
        }
    }
#pragma unroll
    for (int j = 0; j < 8; ++j)
        out[(size_t)(c0 + j) * HW + p] = acc[j];
}

// ---------------------------------------------------------------------------
// Workspace (peak ~26.5 MB):
//   [0, 4M)        inp_t  bf16 [4096][512]              (live to end)
//   [4M, 15.25M)   W1p    256 x 46080 B                 (dead after conv1)
//       reuse:     hid2_t @4M  bf16 [8][4096][64] (4MB)
//                  hid3_t @8M  bf16 [8][4096][32] (2MB)
//                  oa     @10.5M fp32 [8][18][4096] (2.25MB)
//   [16M, 17.5M)   W2p    32 x 46080 B
//   [17.5M, 18M)   W3p    16 x 23552 B
//   [18M, 18.5M)   W4p     8 x 23552 B
//   [18.5M, 26.5M) hid1_t bf16 [8][4096][128]           (dead after conv2)
// ---------------------------------------------------------------------------
extern "C" void kernel_launch(void* const* d_in, const int* in_sizes, int n_in,
                              void* d_out, int out_size, void* d_ws, size_t ws_size,
                              hipStream_t stream)
{
    (void)in_sizes; (void)n_in; (void)out_size; (void)ws_size;
    const float* gar  = (const float*)d_in[0];
    const float* cond = (const float*)d_in[1];
    const float* mask = (const float*)d_in[2];
    const float* W1   = (const float*)d_in[3];
    const float* b1   = (const float*)d_in[4];
    const float* W2   = (const float*)d_in[5];
    const float* b2   = (const float*)d_in[6];
    const float* W3   = (const float*)d_in[7];
    const float* b3   = (const float*)d_in[8];
    const float* W4   = (const float*)d_in[9];
    const float* b4   = (const float*)d_in[10];
    float* out = (float*)d_out;

    char* ws = (char*)d_ws;
    short* inp_t  = (short*)(ws);
    char*  W1p    = ws + (4u << 20);
    short* hid2_t = (short*)(ws + (4u << 20));          // overlays dead W1p
    short* hid3_t = (short*)(ws + (8u << 20));          // overlays dead W1p
    float* oa     = (float*)(ws + (10u << 20) + (512u << 10));
    char*  W2p    = ws + (16u << 20);
    char*  W3p    = ws + (17u << 20) + (512u << 10);
    char*  W4p    = ws + (18u << 20);
    short* hid1_t = (short*)(ws + (18u << 20) + (512u << 10));

    pack_input<<<dim3(128, 16), 256, 0, stream>>>(gar, cond, inp_t);
    pack_w<512, 128, 64, 2><<<256, 256, 0, stream>>>(W1, W1p);
    pack_w<128,  64, 64, 1><<< 32, 256, 0, stream>>>(W2, W2p);
    pack_w< 64,  32, 32, 1><<< 16, 256, 0, stream>>>(W3, W3p);
    pack_w< 32,  18, 32, 1><<<  8, 256, 0, stream>>>(W4, W4p);

    // conv1: 512->128, ROWS=4, BN=64, OF=4, NT=2, pixel-major out, leaky
    conv_mfma<512, 128, 64, 4, 4, 2, true, true, false>
        <<<256, 256, 0, stream>>>(inp_t, W1p, b1, hid1_t);
    // conv2: 128->64, ROWS=2, BN=64, OF=2, NT=1, pixel-major out, leaky
    conv_mfma<128, 64, 64, 2, 2, 1, true, true, false>
        <<<256, 256, 0, stream>>>(hid1_t, W2p, b2, hid2_t);
    // conv3: 64->32, ROWS=2, BN=32, OF=1, NT=1, pixel-major out, leaky
    conv_mfma<64, 32, 32, 2, 1, 1, true, true, false>
        <<<256, 256, 0, stream>>>(hid2_t, W3p, b3, hid3_t);
    // conv4: 32->18 (pad 32), ROWS=2, BN=32, OF=1, NT=1, ch-major fp32, linear
    conv_mfma<32, 18, 32, 2, 1, 1, false, false, true>
        <<<256, 256, 0, stream>>>(hid3_t, W4p, b4, oa);

    warp_combine_kernel<<<512, 256, 0, stream>>>(oa, inp_t, mask, out);
}

// Round 9
// 214.812 us; speedup vs baseline: 8.8831x; 1.1860x over previous
//
#include <hip/hip_runtime.h>
#include <hip/hip_bf16.h>

typedef __hip_bfloat16 bf16;
typedef unsigned short ushort8v __attribute__((ext_vector_type(8)));
typedef short  s16x4  __attribute__((ext_vector_type(4)));
typedef short  bf16x8 __attribute__((ext_vector_type(8)));   // 8 bf16 (4 VGPRs)
typedef float  f32x4  __attribute__((ext_vector_type(4)));

#define HW 4096
#define IMG_W 64

__device__ __forceinline__ float b2f(bf16 v) { return __bfloat162float(v); }
__device__ __forceinline__ float bfbits2f(unsigned short u) {
    return __uint_as_float(((unsigned int)u) << 16);
}
__device__ __forceinline__ short f2bs(float f) {
    bf16 h = __float2bfloat16(f);
    return *reinterpret_cast<short*>(&h);
}

// async global->LDS, 16B per lane (wave-uniform LDS base + lane*16 scatter).
__device__ __forceinline__ void gl_lds16(const void* g, void* s) {
    __builtin_amdgcn_global_load_lds(
        (const __attribute__((address_space(1))) unsigned int*)g,
        (__attribute__((address_space(3))) unsigned int*)s, 16, 0, 0);
}

// ---------------------------------------------------------------------------
// pack_input: concat(gar,cond) fp32 [512][4096] -> inp_t bf16 [4096][512]
// (pixel-major). inp_t[:, 0:256] doubles as gar_t for the warp kernel.
// ---------------------------------------------------------------------------
__global__ __launch_bounds__(256)
void pack_input(const float* __restrict__ gar, const float* __restrict__ cond,
                short* __restrict__ outp)
{
    __shared__ __align__(16) float tile[32][33];
    int bx = blockIdx.x;               // px tile (128)
    int by = blockIdx.y;               // ch tile (16)
    int tx = threadIdx.x & 31;
    int ty = threadIdx.x >> 5;
#pragma unroll
    for (int i = 0; i < 4; ++i) {
        int c = by * 32 + ty + i * 8;
        const float* src = (c < 256) ? (gar + (size_t)c * HW)
                                     : (cond + (size_t)(c - 256) * HW);
        tile[ty + i * 8][tx] = src[bx * 32 + tx];
    }
    __syncthreads();
#pragma unroll
    for (int i = 0; i < 4; ++i) {
        int p = bx * 32 + ty + i * 8;
        outp[(size_t)p * 512 + by * 32 + tx] = f2bs(tile[tx][ty + i * 8]);
    }
}

// ---------------------------------------------------------------------------
// pack_w device body: W fp32 [G][CREAL][CIN][3][3] -> bf16 blocks
// [g][nt][cc][BN oc][9 tap][40 ic] (ic: 32 payload + 8 zero pad; oc zero-pad
// beyond CREAL), padded to BLKB bytes for wave-wide global_load_lds staging.
// ---------------------------------------------------------------------------
template<int CIN, int CREAL, int BN, int NT>
__device__ void pack_w_dev(const float* __restrict__ wgt, char* __restrict__ wp,
                           int bx, short* sT)
{
    constexpr int NCC  = CIN / 32;
    constexpr int BLKB = ((BN * 720 + 1023) / 1024) * 1024;

    const int t  = threadIdx.x;
    const int cc = bx % NCC;
    const int nt = (bx / NCC) % NT;
    const int g  = bx / (NT * NCC);

    for (int i = t; i < BN * 90; i += 256)     // zero all (covers pads)
        reinterpret_cast<s16x4*>(sT)[i] = s16x4{0, 0, 0, 0};
    __syncthreads();

    int ocmax = CREAL - nt * BN; if (ocmax > BN) ocmax = BN;
    const size_t base = ((size_t)(g * CREAL + nt * BN) * CIN + cc * 32) * 9;
    for (int i = t; i < ocmax * 288; i += 256) {
        int oc = i / 288;
        int r  = i % 288;                      // ic*9 + tap
        int ic = r / 9, tap = r % 9;
        sT[oc * 360 + tap * 40 + ic] = f2bs(wgt[base + (size_t)oc * CIN * 9 + r]);
    }
    __syncthreads();

    const char* src = (const char*)sT;
    char* dst = wp + (size_t)bx * BLKB;
    for (int i = t; i < BLKB / 8; i += 256) {
        s16x4 v = (i * 8 < BN * 720)
            ? *reinterpret_cast<const s16x4*>(src + (size_t)i * 8)
            : s16x4{0, 0, 0, 0};
        *reinterpret_cast<s16x4*>(dst + (size_t)i * 8) = v;
    }
}

// All four weight packs in one launch (block-range dispatch; uniform per block)
__global__ __launch_bounds__(256)
void pack_all(const float* __restrict__ W1, const float* __restrict__ W2,
              const float* __restrict__ W3, const float* __restrict__ W4,
              char* W1p, char* W2p, char* W3p, char* W4p)
{
    __shared__ __align__(16) short sT[64 * 9 * 40];
    int bx = blockIdx.x;
    if (bx < 256)      pack_w_dev<512, 128, 64, 2>(W1, W1p, bx,       sT);
    else if (bx < 288) pack_w_dev<128,  64, 64, 1>(W2, W2p, bx - 256, sT);
    else if (bx < 304) pack_w_dev< 64,  32, 32, 1>(W3, W3p, bx - 288, sT);
    else               pack_w_dev< 32,  18, 32, 1>(W4, W4p, bx - 304, sT);
}

// ---------------------------------------------------------------------------
// Implicit-GEMM 3x3 SAME conv, bf16 MFMA 16x16x32, TLP-pipelined.
// Single sB buffer keeps LDS <= 78 KB -> 2 blocks/CU co-resident; one block's
// compute covers the other's DMA drain/barrier (m114 wave-level overlap).
// Register prefetch of sA(cc+1) during compute hides the global-load latency.
// ---------------------------------------------------------------------------
template<int ICP, int CREAL, int BN, int ROWS, int OF, int NT,
         bool PIXMAJ_OUT, bool LEAKY, bool OUT_F32>
__global__ __launch_bounds__(256, 2)
void conv_mfma(const short* __restrict__ inp, const char* __restrict__ wp,
               const float* __restrict__ bias, void* __restrict__ outv)
{
    constexpr int NCC  = ICP / 32;
    constexpr int HALO = ROWS + 2;
    constexpr int NPT  = 4096 / (ROWS * 64);
    constexpr int BLKB = ((BN * 720 + 1023) / 1024) * 1024;
    constexpr int RNDS = BLKB / 1024;

    __shared__ __align__(16) short sA[HALO][66][40];
    __shared__ __align__(16) char  sBraw[BLKB];
    const short (*sB)[9][40] = reinterpret_cast<const short(*)[9][40]>(sBraw);

    const int b  = blockIdx.x;
    const int g  = b & 7;                     // XCD swizzle: group per XCD
    const int r_ = b >> 3;
    const int pt = r_ % NPT;
    const int nt = r_ / NPT;
    const int r0 = pt * ROWS;

    const int t    = threadIdx.x;
    const int wave = t >> 6, lane = t & 63;
    const int l15  = lane & 15, quad = lane >> 4;
    const int row_l = (ROWS == 4) ? wave : (wave & 1);
    const int ocw   = (ROWS == 4) ? 0 : (wave >> 1) * (BN / 2);
    const int k0    = quad * 8;

    const size_t gpix = (ICP == 512) ? 0 : ((size_t)g * 4096);
    const char*  wb   = wp + (size_t)((g * NT + nt) * NCC) * BLKB;

    // per-thread sA staging slot: 16B unit (q-quarter of 32 ic) per halo row
    const int aq   = t & 3;
    const int acol = (t >> 2) & 63;

    bf16x8 pre[HALO];

    auto stageA_load = [&](int cc) {
#pragma unroll
        for (int j = 0; j < HALO; ++j) {
            int gy = r0 - 1 + j;
            bf16x8 v = {0, 0, 0, 0, 0, 0, 0, 0};
            if (gy >= 0 && gy < 64)
                v = *reinterpret_cast<const bf16x8*>(
                    inp + ((gpix + gy * 64 + acol) * ICP + cc * 32 + aq * 8));
            pre[j] = v;
        }
    };
    auto stageA_write = [&]() {
#pragma unroll
        for (int j = 0; j < HALO; ++j)
            *reinterpret_cast<bf16x8*>(&sA[j][acol + 1][aq * 8]) = pre[j];
    };
    auto stageB = [&](int cc) {
        const char* wsrc = wb + (size_t)cc * BLKB;
        for (int r = wave; r < RNDS; r += 4)
            gl_lds16(wsrc + r * 1024 + lane * 16, (char*)sBraw + r * 1024);
    };

    f32x4 acc[OF][4];
#pragma unroll
    for (int o = 0; o < OF; ++o)
#pragma unroll
        for (int p = 0; p < 4; ++p)
#pragma unroll
            for (int r = 0; r < 4; ++r) acc[o][p][r] = 0.f;

    // zero the two x-pad columns once (5 b128 units per (row,col))
    for (int i = t; i < HALO * 2 * 5; i += 256) {
        int rr = i / 10;
        int cp = ((i / 5) & 1) ? 65 : 0;
        int q  = i % 5;
        bf16x8 z = {0, 0, 0, 0, 0, 0, 0, 0};
        *reinterpret_cast<bf16x8*>(&sA[rr][cp][q * 8]) = z;
    }

    // prologue: stage phase 0
    stageB(0);
    stageA_load(0);
    stageA_write();

    for (int cc = 0; cc < NCC; ++cc) {
        __syncthreads();               // sB(cc) DMA drained, sA(cc) visible
        if (cc + 1 < NCC) stageA_load(cc + 1);   // global -> regs, no LDS touch

#pragma unroll
        for (int dy = 0; dy < 3; ++dy) {
#pragma unroll
            for (int dx = 0; dx < 3; ++dx) {
                bf16x8 pF[4];
#pragma unroll
                for (int p = 0; p < 4; ++p)
                    pF[p] = *reinterpret_cast<const bf16x8*>(
                        &sA[row_l + dy][p * 16 + l15 + dx][k0]);
                bf16x8 wF[OF];
#pragma unroll
                for (int o = 0; o < OF; ++o)
                    wF[o] = *reinterpret_cast<const bf16x8*>(
                        &sB[ocw + o * 16 + l15][dy * 3 + dx][k0]);
#pragma unroll
                for (int o = 0; o < OF; ++o)
#pragma unroll
                    for (int p = 0; p < 4; ++p)
                        acc[o][p] = __builtin_amdgcn_mfma_f32_16x16x32_bf16(
                            wF[o], pF[p], acc[o][p], 0, 0, 0);
            }
        }
        __syncthreads();               // all reads of sA(cc)/sB(cc) done
        if (cc + 1 < NCC) {
            stageB(cc + 1);            // DMA next weights into the single buf
            stageA_write();            // commit prefetched sA regs
        }
    }

    // ---- epilogue. C/D: m(oc) = quad*4+reg, n(pixel) = l15.
    const int prow = r0 + row_l;
#pragma unroll
    for (int o = 0; o < OF; ++o)
#pragma unroll
        for (int reg = 0; reg < 4; ++reg) {
            const int ocl = ocw + o * 16 + quad * 4 + reg;
            const int ocg = nt * BN + ocl;
            if (ocg < CREAL) {
                const float bv = bias[g * CREAL + ocg];
                if (PIXMAJ_OUT) {
                    short* outp = (short*)outv;
                    const size_t pixbase = ((size_t)g * 4096 + prow * 64);
#pragma unroll
                    for (int p = 0; p < 4; ++p) {
                        float v = acc[o][p][reg] + bv;
                        if (LEAKY) v = v >= 0.f ? v : 0.1f * v;
                        outp[(pixbase + p * 16 + l15) * (NT * BN) + ocg] = f2bs(v);
                    }
                } else if (OUT_F32) {
                    float* outp = (float*)outv;
                    const size_t base = ((size_t)(g * CREAL + ocg)) * HW + prow * IMG_W;
#pragma unroll
                    for (int p = 0; p < 4; ++p) {
                        float v = acc[o][p][reg] + bv;
                        if (LEAKY) v = v >= 0.f ? v : 0.1f * v;
                        outp[base + p * 16 + l15] = v;
                    }
                } else {
                    short* outp = (short*)outv;
                    const size_t base = ((size_t)(g * CREAL + ocg)) * HW + prow * IMG_W;
#pragma unroll
                    for (int p = 0; p < 4; ++p) {
                        float v = acc[o][p][reg] + bv;
                        if (LEAKY) v = v >= 0.f ? v : 0.1f * v;
                        outp[base + p * 16 + l15] = f2bs(v);
                    }
                }
            }
        }
}

// ---------------------------------------------------------------------------
// Fused softmax-over-groups + bilinear params + warp + combine (fp32 out).
// gar channels come from inp_t rows (stride 512, first 256 entries).
// ---------------------------------------------------------------------------
__global__ __launch_bounds__(256)
void warp_combine_kernel(const float* __restrict__ oa,
                         const short* __restrict__ inp_t,
                         const float* __restrict__ mask,
                         float* __restrict__ out)
{
    __shared__ __align__(16) float4 sWts[8][6][8];
    __shared__ __align__(16) int4   sIdx[8][6][8];

    const int t = threadIdx.x;

    if (t < 48) {
        int lp = t / 6;
        int k  = t % 6;
        int p  = blockIdx.x * 8 + lp;
        int x  = p & 63, y = p >> 6;

        float l[8];
        float m = -1e30f;
#pragma unroll
        for (int g = 0; g < 8; ++g) {
            l[g] = oa[(size_t)(g * 18 + 12 + k) * HW + p];
            m = fmaxf(m, l[g]);
        }
        float s = 0.f;
#pragma unroll
        for (int g = 0; g < 8; ++g) { l[g] = __expf(l[g] - m); s += l[g]; }
        float inv = 1.f / s;

#pragma unroll
        for (int g = 0; g < 8; ++g) {
            float a  = l[g] * inv;
            float ox = oa[(size_t)(g * 18 + 2 * k)     * HW + p];
            float oy = oa[(size_t)(g * 18 + 2 * k + 1) * HW + p];
            float sx = fminf(fmaxf(((float)x + ox) * (64.f / 63.f) - 0.5f, 0.f), 63.f);
            float sy = fminf(fmaxf(((float)y + oy) * (64.f / 63.f) - 0.5f, 0.f), 63.f);
            float fx0 = floorf(sx), fy0 = floorf(sy);
            int   x0 = (int)fx0,    y0i = (int)fy0;
            float wx = sx - fx0,    wy = sy - fy0;
            int   x1 = min(x0 + 1, 63), y1 = min(y0i + 1, 63);
            sWts[lp][k][g] = make_float4(a * (1.f - wy) * (1.f - wx),
                                         a * (1.f - wy) * wx,
                                         a * wy * (1.f - wx),
                                         a * wy * wx);
            sIdx[lp][k][g] = make_int4(y0i * 64 + x0, y0i * 64 + x1,
                                       y1  * 64 + x0, y1  * 64 + x1);
        }
    }
    __syncthreads();

    const int lp = t >> 5;
    const int p  = blockIdx.x * 8 + lp;
    const int c0 = (t & 31) * 8;

    float acc[8];
#pragma unroll
    for (int j = 0; j < 8; ++j) acc[j] = 0.f;

    for (int g = 0; g < 8; ++g) {
        float4 m0 = *reinterpret_cast<const float4*>(mask + g * 256 + c0);
        float4 m1 = *reinterpret_cast<const float4*>(mask + g * 256 + c0 + 4);
        float mk[8] = {m0.x, m0.y, m0.z, m0.w, m1.x, m1.y, m1.z, m1.w};
#pragma unroll
        for (int k = 0; k < 6; ++k) {
            float4 w  = sWts[lp][k][g];
            int4   id = sIdx[lp][k][g];
            ushort8v v00 = *reinterpret_cast<const ushort8v*>(inp_t + (size_t)id.x * 512 + c0);
            ushort8v v01 = *reinterpret_cast<const ushort8v*>(inp_t + (size_t)id.y * 512 + c0);
            ushort8v v10 = *reinterpret_cast<const ushort8v*>(inp_t + (size_t)id.z * 512 + c0);
            ushort8v v11 = *reinterpret_cast<const ushort8v*>(inp_t + (size_t)id.w * 512 + c0);
#pragma unroll
            for (int j = 0; j < 8; ++j) {
                float sv = w.x * bfbits2f(v00[j]) + w.y * bfbits2f(v01[j])
                         + w.z * bfbits2f(v10[j]) + w.w * bfbits2f(v11[j]);
                acc[j] = fmaf(mk[j], sv, acc[j]);
            }
        }
    }
#pragma unroll
    for (int j = 0; j < 8; ++j)
        out[(size_t)(c0 + j) * HW + p] = acc[j];
}

// ---------------------------------------------------------------------------
// Workspace (peak ~26.5 MB):
//   [0, 4M)        inp_t  bf16 [4096][512]              (live to end)
//   [4M, 15.25M)   W1p    256 x 46080 B                 (dead after conv1)
//       reuse:     hid2_t @4M  bf16 [8][4096][64] (4MB)
//                  hid3_t @8M  bf16 [8][4096][32] (2MB)
//                  oa     @10.5M fp32 [8][18][4096] (2.25MB)
//   [16M, 17.5M)   W2p    32 x 46080 B
//   [17.5M, 18M)   W3p    16 x 23552 B
//   [18M, 18.5M)   W4p     8 x 23552 B
//   [18.5M, 26.5M) hid1_t bf16 [8][4096][128]           (dead after conv2)
// ---------------------------------------------------------------------------
extern "C" void kernel_launch(void* const* d_in, const int* in_sizes, int n_in,
                              void* d_out, int out_size, void* d_ws, size_t ws_size,
                              hipStream_t stream)
{
    (void)in_sizes; (void)n_in; (void)out_size; (void)ws_size;
    const float* gar  = (const float*)d_in[0];
    const float* cond = (const float*)d_in[1];
    const float* mask = (const float*)d_in[2];
    const float* W1   = (const float*)d_in[3];
    const float* b1   = (const float*)d_in[4];
    const float* W2   = (const float*)d_in[5];
    const float* b2   = (const float*)d_in[6];
    const float* W3   = (const float*)d_in[7];
    const float* b3   = (const float*)d_in[8];
    const float* W4   = (const float*)d_in[9];
    const float* b4   = (const float*)d_in[10];
    float* out = (float*)d_out;

    char* ws = (char*)d_ws;
    short* inp_t  = (short*)(ws);
    char*  W1p    = ws + (4u << 20);
    short* hid2_t = (short*)(ws + (4u << 20));          // overlays dead W1p
    short* hid3_t = (short*)(ws + (8u << 20));          // overlays dead W1p
    float* oa     = (float*)(ws + (10u << 20) + (512u << 10));
    char*  W2p    = ws + (16u << 20);
    char*  W3p    = ws + (17u << 20) + (512u << 10);
    char*  W4p    = ws + (18u << 20);
    short* hid1_t = (short*)(ws + (18u << 20) + (512u << 10));

    pack_input<<<dim3(128, 16), 256, 0, stream>>>(gar, cond, inp_t);
    pack_all<<<312, 256, 0, stream>>>(W1, W2, W3, W4, W1p, W2p, W3p, W4p);

    // conv1: 512->128, ROWS=4, BN=64, OF=4, NT=2, pixel-major out, leaky
    conv_mfma<512, 128, 64, 4, 4, 2, true, true, false>
        <<<256, 256, 0, stream>>>(inp_t, W1p, b1, hid1_t);
    // conv2: 128->64, ROWS=2, BN=64, OF=2, NT=1, pixel-major out, leaky
    conv_mfma<128, 64, 64, 2, 2, 1, true, true, false>
        <<<256, 256, 0, stream>>>(hid1_t, W2p, b2, hid2_t);
    // conv3: 64->32, ROWS=2, BN=32, OF=1, NT=1, pixel-major out, leaky
    conv_mfma<64, 32, 32, 2, 1, 1, true, true, false>
        <<<256, 256, 0, stream>>>(hid2_t, W3p, b3, hid3_t);
    // conv4: 32->18 (pad 32), ROWS=2, BN=32, OF=1, NT=1, ch-major fp32, linear
    conv_mfma<32, 18, 32, 2, 1, 1, false, false, true>
        <<<256, 256, 0, stream>>>(hid3_t, W4p, b4, oa);

    warp_combine_kernel<<<512, 256, 0, stream>>>(oa, inp_t, mask, out);
}